// Round 6
// baseline (479.017 us; speedup 1.0000x reference)
//
#include <hip/hip_runtime.h>
#include <math.h>

constexpr int Bn = 4, Cc = 128, On = 128, Hh = 160, Ww = 160, Kk = 9;
constexpr int HW = Hh * Ww;          // 25600

typedef __attribute__((ext_vector_type(8))) short s16x8;
typedef __attribute__((ext_vector_type(4))) float f32x4;

__device__ inline float bf2f(short s) {
    union { float f; unsigned u; } v;
    v.u = ((unsigned)(unsigned short)s) << 16;
    return v.f;
}
__device__ inline short f2bf(float f) {
    union { float f; unsigned u; } v;
    v.f = f;
    unsigned r = v.u + 0x7fffu + ((v.u >> 16) & 1u);   // RNE
    return (short)(r >> 16);
}

// ---------------------------------------------------------------------------
// Kernel A1: x (NCHW f32) -> xT (NHWC bf16 hi) + xLo (NHWC bf16 lo).
// ---------------------------------------------------------------------------
__global__ __launch_bounds__(256) void to_nhwc(const float* __restrict__ x,
                                               short* __restrict__ xT,
                                               short* __restrict__ xLo) {
    __shared__ float tile[128][65];
    const int t = threadIdx.x;
    const int p0 = blockIdx.x * 64;
    const int b = blockIdx.y;
#pragma unroll
    for (int i = 0; i < 32; ++i) {
        int c = i * 4 + (t >> 6);
        tile[c][t & 63] = x[((size_t)b * Cc + c) * HW + p0 + (t & 63)];
    }
    __syncthreads();
    const int px = t >> 2, cq = t & 3;
    short* dsth = xT  + ((size_t)(b * HW) + p0 + px) * Cc;
    short* dstl = xLo + ((size_t)(b * HW) + p0 + px) * Cc;
#pragma unroll
    for (int j = 0; j < 8; ++j) {
        int c0 = cq * 4 + j * 16;
        short4 vh, vl;
        float f0 = tile[c0 + 0][px], f1 = tile[c0 + 1][px];
        float f2 = tile[c0 + 2][px], f3 = tile[c0 + 3][px];
        vh.x = f2bf(f0); vh.y = f2bf(f1); vh.z = f2bf(f2); vh.w = f2bf(f3);
        vl.x = f2bf(f0 - bf2f(vh.x));
        vl.y = f2bf(f1 - bf2f(vh.y));
        vl.z = f2bf(f2 - bf2f(vh.z));
        vl.w = f2bf(f3 - bf2f(vh.w));
        *(short4*)(dsth + c0) = vh;
        *(short4*)(dstl + c0) = vl;
    }
}

// ---------------------------------------------------------------------------
// Kernel A2: wt (O,C,3,3) f32 -> wb[k][o][c] bf16
// ---------------------------------------------------------------------------
__global__ void prep_w(const float* __restrict__ wt, short* __restrict__ wb) {
    int idx = blockIdx.x * 256 + threadIdx.x;     // K*O*C = 147456
    if (idx >= Kk * On * Cc) return;
    int c = idx & 127;
    int o = (idx >> 7) & 127;
    int k = idx >> 14;
    wb[idx] = f2bf(wt[(o * Cc + c) * 9 + k]);
}

// ---------------------------------------------------------------------------
// Kernel A3: offset/mask weights -> wofm_{hi,lo}[k][ch32][c].
// ---------------------------------------------------------------------------
__global__ void prep_wofm(const float* __restrict__ w_off,
                          const float* __restrict__ w_mask,
                          short* __restrict__ wh, short* __restrict__ wl) {
    int idx = blockIdx.x * 256 + threadIdx.x;     // 9*32*128 = 36864
    if (idx >= Kk * 32 * Cc) return;
    int c = idx & 127;
    int ch = (idx >> 7) & 31;
    int k = idx >> 12;
    float v = 0.f;
    if (ch < 18)      v = w_off[(ch * Cc + c) * 9 + k];
    else if (ch < 27) v = w_mask[((ch - 18) * Cc + c) * 9 + k];
    short hi = f2bf(v);
    wh[idx] = hi;
    wl[idx] = f2bf(v - bf2f(hi));
}

// ---------------------------------------------------------------------------
// Kernel B: offset/mask conv via MFMA, hi/lo split. NO LDS, no barriers:
// A-fragments read directly from L2/L1-resident xT/xLo (clamped col +
// select-zero; wave-uniform row skip), B from global (as before).
// Grid: flat 1600, XCD-chunked swizzle.
// ---------------------------------------------------------------------------
__global__ __launch_bounds__(256) void offmask_mfma(
    const short* __restrict__ xT, const short* __restrict__ xLo,
    const short* __restrict__ wh, const short* __restrict__ wl,
    const float* __restrict__ b_off, const float* __restrict__ b_mask,
    float* __restrict__ dy_o, float* __restrict__ dx_o, float* __restrict__ mk_o)
{
    // flat grid 1600 = 8 XCDs x 200 contiguous (b, hband, wtile) units
    const int g = blockIdx.x;
    const int orig = (g & 7) * 200 + (g >> 3);
    const int b  = orig / 400;
    const int rem = orig % 400;
    const int h0 = (rem / 10) * 4;
    const int w0 = (rem % 10) * 16;

    const int t = threadIdx.x;
    const int lane = t & 63, wid = t >> 6;
    const int i  = lane & 15;
    const int kb = (lane >> 4) * 8;

    const short* xh_b = xT  + (size_t)b * HW * Cc;
    const short* xl_b = xLo + (size_t)b * HW * Cc;

    const s16x8 vzero = {0, 0, 0, 0, 0, 0, 0, 0};

    f32x4 acc[2];
    acc[0] = (f32x4){0.f, 0.f, 0.f, 0.f};
    acc[1] = (f32x4){0.f, 0.f, 0.f, 0.f};

#pragma unroll
    for (int ky = 0; ky < 3; ++ky) {
        const int r = h0 + wid + ky - 1;          // wave-uniform
        if ((unsigned)r >= (unsigned)Hh) continue; // OOB row -> exact-zero terms
#pragma unroll
        for (int kxi = 0; kxi < 3; ++kxi) {
            const int col = w0 - 1 + i + kxi;
            const int ccol = min(max(col, 0), Ww - 1);
            const bool colOK = ((unsigned)col < (unsigned)Ww);
            const short* pa = xh_b + ((size_t)(r * Ww + ccol)) * Cc + kb;
            const short* pl = xl_b + ((size_t)(r * Ww + ccol)) * Cc + kb;
            s16x8 ah[4], al[4];
#pragma unroll
            for (int kk = 0; kk < 4; ++kk) {
                ah[kk] = *(const s16x8*)(pa + kk * 32);
                al[kk] = *(const s16x8*)(pl + kk * 32);
                if (!colOK) { ah[kk] = vzero; al[kk] = vzero; }
            }
            const int k = ky * 3 + kxi;
#pragma unroll
            for (int tile = 0; tile < 2; ++tile) {
                const short* bp = wh + ((size_t)k * 32 + tile * 16 + i) * Cc + kb;
                const short* lp = wl + ((size_t)k * 32 + tile * 16 + i) * Cc + kb;
                s16x8 bh[4], bl[4];
#pragma unroll
                for (int kk = 0; kk < 4; ++kk) {
                    bh[kk] = *(const s16x8*)(bp + kk * 32);
                    bl[kk] = *(const s16x8*)(lp + kk * 32);
                }
#pragma unroll
                for (int kk = 0; kk < 4; ++kk) {
                    acc[tile] = __builtin_amdgcn_mfma_f32_16x16x32_bf16(ah[kk], bh[kk], acc[tile], 0, 0, 0);
                    acc[tile] = __builtin_amdgcn_mfma_f32_16x16x32_bf16(al[kk], bh[kk], acc[tile], 0, 0, 0);
                    acc[tile] = __builtin_amdgcn_mfma_f32_16x16x32_bf16(ah[kk], bl[kk], acc[tile], 0, 0, 0);
                }
            }
        }
    }

    // ---- epilogue: D col=lane&15 -> ch, row=(lane>>4)*4+reg -> px ----
    const int hr = h0 + wid;
#pragma unroll
    for (int tile = 0; tile < 2; ++tile) {
        int ch = tile * 16 + i;
#pragma unroll
        for (int reg = 0; reg < 4; ++reg) {
            int pxo = (lane >> 4) * 4 + reg;
            int p = hr * Ww + w0 + pxo;
            float v = acc[tile][reg];
            if (ch < 18) {
                int k = ch >> 1;
                v += b_off[ch];
                if (ch & 1) dx_o[(size_t)(b * 9 + k) * HW + p] = v;
                else        dy_o[(size_t)(b * 9 + k) * HW + p] = v;
            } else if (ch < 27) {
                int k = ch - 18;
                v += b_mask[k];
                mk_o[(size_t)(b * 9 + k) * HW + p] = 1.f / (1.f + expf(-v));
            }
        }
    }
}

// ---------------------------------------------------------------------------
// Kernel C: main deformable conv. Deltas vs r5 (each mechanism-isolated):
//  (1) B-fragments read DIRECTLY from global wb (L2-resident) -- no w_lds,
//      no staging phase, no 8-way-conflicted LDS B-reads.
//  (2) barriers 3 -> 2 per k: gather->MFMA is same-wave (val_lds rows
//      pm..pm+15 written and read by the same wave), so no barrier there.
//  LDS drops 51.2 KB -> 18.4 KB => ~6-8 blocks/CU.
//  Gather, A-path, swizzle, epilogue: byte-identical to r5.
// ---------------------------------------------------------------------------
__global__ __launch_bounds__(256) void dconv_main(
    const short* __restrict__ xT,    // [b][hw][c] bf16
    const short* __restrict__ wb,    // [k][o][c] bf16
    const float* __restrict__ bias,
    const float* __restrict__ dy_i, const float* __restrict__ dx_i,
    const float* __restrict__ mk_i,
    float* __restrict__ out)
{
    __shared__ short val_lds[64 * 128];  // 16 KB, byte ^= (px&7)<<4
    __shared__ float wgt_s[4][64];
    __shared__ int   idx_s[4][64];

    // XCD-chunked swizzle: 1600 blocks = 8 XCDs x 200 contiguous (b,tile).
    const int g = blockIdx.x;
    const int orig = (g & 7) * 200 + (g >> 3);
    const int b = orig / 400;
    const int p0 = (orig % 400) * 64;

    const int t = threadIdx.x;
    const int lane = t & 63;
    const int wid = t >> 6;
    const int pm = wid * 16;             // wave's pixel base

    f32x4 acc[8];
#pragma unroll
    for (int i = 0; i < 8; ++i) acc[i] = (f32x4){0.f, 0.f, 0.f, 0.f};

    const short* xb = xT + (size_t)b * HW * Cc + (lane & 31) * 4;

    for (int k = 0; k < Kk; ++k) {
        // ---- 1. bilinear setup: 256 threads = 64 px x 4 corners ----
        {
            int px = t & 63;
            int cr = t >> 6;
            int p = p0 + px;
            int h = p / Ww, w = p % Ww;
            size_t base = (size_t)(b * 9 + k) * HW + p;
            float dyv = dy_i[base], dxv = dx_i[base], m = mk_i[base];
            float py  = (float)(h + (k / 3) - 1) + dyv;
            float pxf = (float)(w + (k % 3) - 1) + dxv;
            float y0f = floorf(py), x0f = floorf(pxf);
            float ly = py - y0f, lx = pxf - x0f;
            int y0 = (int)y0f, x0 = (int)x0f;
            int iy = y0 + (cr >> 1), ix = x0 + (cr & 1);
            bool ok = ((unsigned)iy < (unsigned)Hh) && ((unsigned)ix < (unsigned)Ww);
            float wy = (cr >> 1) ? ly : (1.f - ly);
            float wx = (cr & 1) ? lx : (1.f - lx);
            int cy = min(max(iy, 0), Hh - 1);
            int cx = min(max(ix, 0), Ww - 1);
            idx_s[cr][px] = cy * Ww + cx;
            wgt_s[cr][px] = ok ? (wy * wx * m) : 0.f;
        }
        __syncthreads();

        // ---- 2. gather into val_lds: wave = its own 16 px ----
        {
            const int cq = lane & 31;
#pragma unroll
            for (int pp = 0; pp < 16; pp += 2) {
                int pxl = pm + pp + (lane >> 5);
                float w0 = wgt_s[0][pxl], w1 = wgt_s[1][pxl];
                float w2 = wgt_s[2][pxl], w3 = wgt_s[3][pxl];
                size_t i0 = (size_t)idx_s[0][pxl] * Cc;
                size_t i1 = (size_t)idx_s[1][pxl] * Cc;
                size_t i2 = (size_t)idx_s[2][pxl] * Cc;
                size_t i3 = (size_t)idx_s[3][pxl] * Cc;
                short4 v0 = *(const short4*)(xb + i0);
                short4 v1 = *(const short4*)(xb + i1);
                short4 v2 = *(const short4*)(xb + i2);
                short4 v3 = *(const short4*)(xb + i3);
                float s0 = w0 * bf2f(v0.x) + w1 * bf2f(v1.x) + w2 * bf2f(v2.x) + w3 * bf2f(v3.x);
                float s1 = w0 * bf2f(v0.y) + w1 * bf2f(v1.y) + w2 * bf2f(v2.y) + w3 * bf2f(v3.y);
                float s2 = w0 * bf2f(v0.z) + w1 * bf2f(v1.z) + w2 * bf2f(v2.z) + w3 * bf2f(v3.z);
                float s3 = w0 * bf2f(v0.w) + w1 * bf2f(v1.w) + w2 * bf2f(v2.w) + w3 * bf2f(v3.w);
                short4 r;
                r.x = f2bf(s0); r.y = f2bf(s1); r.z = f2bf(s2); r.w = f2bf(s3);
                int byte = (pxl * 256 + cq * 8) ^ ((pxl & 7) << 4);
                *(short4*)((char*)val_lds + byte) = r;
            }
        }

        // ---- 3. MFMA: A from val_lds (same wave), B direct from global ----
        {
            s16x8 afr[4];
            const int pxr = pm + (lane & 15);
            const int kb = (lane >> 4) * 8;       // k-slice base within 32
#pragma unroll
            for (int kk = 0; kk < 4; ++kk) {
                int byte = (pxr * 256 + (kk * 32 + kb) * 2) ^ ((pxr & 7) << 4);
                afr[kk] = *(const s16x8*)((char*)val_lds + byte);
            }
            const short* wbk = wb + (size_t)k * (On * Cc) + (size_t)(lane & 15) * Cc + kb;
#pragma unroll
            for (int ot = 0; ot < 8; ++ot) {
                const short* wp = wbk + ot * 16 * Cc;
                s16x8 bfr[4];
#pragma unroll
                for (int kk = 0; kk < 4; ++kk)
                    bfr[kk] = *(const s16x8*)(wp + kk * 32);
#pragma unroll
                for (int kk = 0; kk < 4; ++kk)
                    acc[ot] = __builtin_amdgcn_mfma_f32_16x16x32_bf16(afr[kk], bfr[kk], acc[ot], 0, 0, 0);
            }
        }
        __syncthreads();   // protects wgt_s/idx_s (WAR) for next k's setup
    }

    // ---- epilogue: D layout col=lane&15 (o), row=(lane>>4)*4+reg (px) ----
#pragma unroll
    for (int ot = 0; ot < 8; ++ot) {
        int o = ot * 16 + (lane & 15);
        float bo = bias[o];
        float4 r;
        r.x = acc[ot][0] + bo;
        r.y = acc[ot][1] + bo;
        r.z = acc[ot][2] + bo;
        r.w = acc[ot][3] + bo;
        *(float4*)(out + ((size_t)(b * On + o)) * HW + p0 + pm + (lane >> 4) * 4) = r;
    }
}

// ---------------------------------------------------------------------------
extern "C" void kernel_launch(void* const* d_in, const int* in_sizes, int n_in,
                              void* d_out, int out_size, void* d_ws, size_t ws_size,
                              hipStream_t stream) {
    const float* x      = (const float*)d_in[0];
    const float* w_off  = (const float*)d_in[1];
    const float* b_off  = (const float*)d_in[2];
    const float* w_mask = (const float*)d_in[3];
    const float* b_mask = (const float*)d_in[4];
    const float* wt     = (const float*)d_in[5];
    const float* bias   = (const float*)d_in[6];
    float* out = (float*)d_out;

    short* xT  = (short*)d_ws;                      // B*HW*C bf16 hi
    short* xLo = xT + (size_t)Bn * HW * Cc;         // B*HW*C bf16 lo
    short* wb  = xLo + (size_t)Bn * HW * Cc;        // K*O*C bf16
    short* wofm_h = wb + Kk * On * Cc;
    short* wofm_l = wofm_h + Kk * 32 * Cc;
    float* dy = (float*)(wofm_l + Kk * 32 * Cc);
    float* dx = dy + (size_t)Bn * 9 * HW;
    float* mk = dx + (size_t)Bn * 9 * HW;

    to_nhwc<<<dim3(HW / 64, Bn), 256, 0, stream>>>(x, xT, xLo);
    prep_w<<<(Kk * On * Cc + 255) / 256, 256, 0, stream>>>(wt, wb);
    prep_wofm<<<(Kk * 32 * Cc + 255) / 256, 256, 0, stream>>>(w_off, w_mask, wofm_h, wofm_l);
    offmask_mfma<<<1600, 256, 0, stream>>>(
        xT, xLo, wofm_h, wofm_l, b_off, b_mask, dy, dx, mk);
    dconv_main<<<1600, 256, 0, stream>>>(
        xT, wb, bias, dy, dx, mk, out);
}

// Round 7
// 349.283 us; speedup vs baseline: 1.3714x; 1.3714x over previous
//
#include <hip/hip_runtime.h>
#include <math.h>

constexpr int Bn = 4, Cc = 128, On = 128, Hh = 160, Ww = 160, Kk = 9;
constexpr int HW = Hh * Ww;          // 25600

typedef __attribute__((ext_vector_type(8))) short s16x8;
typedef __attribute__((ext_vector_type(4))) float f32x4;

__device__ inline float bf2f(short s) {
    union { float f; unsigned u; } v;
    v.u = ((unsigned)(unsigned short)s) << 16;
    return v.f;
}
__device__ inline short f2bf(float f) {
    union { float f; unsigned u; } v;
    v.f = f;
    unsigned r = v.u + 0x7fffu + ((v.u >> 16) & 1u);   // RNE
    return (short)(r >> 16);
}

// ---------------------------------------------------------------------------
// Kernel A1: x (NCHW f32) -> xT (NHWC bf16 hi) + xLo (NHWC bf16 lo).
// ---------------------------------------------------------------------------
__global__ __launch_bounds__(256) void to_nhwc(const float* __restrict__ x,
                                               short* __restrict__ xT,
                                               short* __restrict__ xLo) {
    __shared__ float tile[128][65];
    const int t = threadIdx.x;
    const int p0 = blockIdx.x * 64;
    const int b = blockIdx.y;
#pragma unroll
    for (int i = 0; i < 32; ++i) {
        int c = i * 4 + (t >> 6);
        tile[c][t & 63] = x[((size_t)b * Cc + c) * HW + p0 + (t & 63)];
    }
    __syncthreads();
    const int px = t >> 2, cq = t & 3;
    short* dsth = xT  + ((size_t)(b * HW) + p0 + px) * Cc;
    short* dstl = xLo + ((size_t)(b * HW) + p0 + px) * Cc;
#pragma unroll
    for (int j = 0; j < 8; ++j) {
        int c0 = cq * 4 + j * 16;
        short4 vh, vl;
        float f0 = tile[c0 + 0][px], f1 = tile[c0 + 1][px];
        float f2 = tile[c0 + 2][px], f3 = tile[c0 + 3][px];
        vh.x = f2bf(f0); vh.y = f2bf(f1); vh.z = f2bf(f2); vh.w = f2bf(f3);
        vl.x = f2bf(f0 - bf2f(vh.x));
        vl.y = f2bf(f1 - bf2f(vh.y));
        vl.z = f2bf(f2 - bf2f(vh.z));
        vl.w = f2bf(f3 - bf2f(vh.w));
        *(short4*)(dsth + c0) = vh;
        *(short4*)(dstl + c0) = vl;
    }
}

// ---------------------------------------------------------------------------
// Kernel A2: wt (O,C,3,3) f32 -> wb[k][o][c] bf16
// ---------------------------------------------------------------------------
__global__ void prep_w(const float* __restrict__ wt, short* __restrict__ wb) {
    int idx = blockIdx.x * 256 + threadIdx.x;     // K*O*C = 147456
    if (idx >= Kk * On * Cc) return;
    int c = idx & 127;
    int o = (idx >> 7) & 127;
    int k = idx >> 14;
    wb[idx] = f2bf(wt[(o * Cc + c) * 9 + k]);
}

// ---------------------------------------------------------------------------
// Kernel A3: offset/mask weights -> wofm_{hi,lo}[k][ch32][c].
// ---------------------------------------------------------------------------
__global__ void prep_wofm(const float* __restrict__ w_off,
                          const float* __restrict__ w_mask,
                          short* __restrict__ wh, short* __restrict__ wl) {
    int idx = blockIdx.x * 256 + threadIdx.x;     // 9*32*128 = 36864
    if (idx >= Kk * 32 * Cc) return;
    int c = idx & 127;
    int ch = (idx >> 7) & 31;
    int k = idx >> 12;
    float v = 0.f;
    if (ch < 18)      v = w_off[(ch * Cc + c) * 9 + k];
    else if (ch < 27) v = w_mask[((ch - 18) * Cc + c) * 9 + k];
    short hi = f2bf(v);
    wh[idx] = hi;
    wl[idx] = f2bf(v - bf2f(hi));
}

// ---------------------------------------------------------------------------
// Kernel B: offset/mask conv via MFMA, hi/lo split. NO LDS, no barriers
// (unchanged from round 6 — passed).
// ---------------------------------------------------------------------------
__global__ __launch_bounds__(256) void offmask_mfma(
    const short* __restrict__ xT, const short* __restrict__ xLo,
    const short* __restrict__ wh, const short* __restrict__ wl,
    const float* __restrict__ b_off, const float* __restrict__ b_mask,
    float* __restrict__ dy_o, float* __restrict__ dx_o, float* __restrict__ mk_o)
{
    const int g = blockIdx.x;
    const int orig = (g & 7) * 200 + (g >> 3);
    const int b  = orig / 400;
    const int rem = orig % 400;
    const int h0 = (rem / 10) * 4;
    const int w0 = (rem % 10) * 16;

    const int t = threadIdx.x;
    const int lane = t & 63, wid = t >> 6;
    const int i  = lane & 15;
    const int kb = (lane >> 4) * 8;

    const short* xh_b = xT  + (size_t)b * HW * Cc;
    const short* xl_b = xLo + (size_t)b * HW * Cc;

    const s16x8 vzero = {0, 0, 0, 0, 0, 0, 0, 0};

    f32x4 acc[2];
    acc[0] = (f32x4){0.f, 0.f, 0.f, 0.f};
    acc[1] = (f32x4){0.f, 0.f, 0.f, 0.f};

#pragma unroll
    for (int ky = 0; ky < 3; ++ky) {
        const int r = h0 + wid + ky - 1;          // wave-uniform
        if ((unsigned)r >= (unsigned)Hh) continue; // OOB row -> exact-zero terms
#pragma unroll
        for (int kxi = 0; kxi < 3; ++kxi) {
            const int col = w0 - 1 + i + kxi;
            const int ccol = min(max(col, 0), Ww - 1);
            const bool colOK = ((unsigned)col < (unsigned)Ww);
            const short* pa = xh_b + ((size_t)(r * Ww + ccol)) * Cc + kb;
            const short* pl = xl_b + ((size_t)(r * Ww + ccol)) * Cc + kb;
            s16x8 ah[4], al[4];
#pragma unroll
            for (int kk = 0; kk < 4; ++kk) {
                ah[kk] = *(const s16x8*)(pa + kk * 32);
                al[kk] = *(const s16x8*)(pl + kk * 32);
                if (!colOK) { ah[kk] = vzero; al[kk] = vzero; }
            }
            const int k = ky * 3 + kxi;
#pragma unroll
            for (int tile = 0; tile < 2; ++tile) {
                const short* bp = wh + ((size_t)k * 32 + tile * 16 + i) * Cc + kb;
                const short* lp = wl + ((size_t)k * 32 + tile * 16 + i) * Cc + kb;
                s16x8 bh[4], bl[4];
#pragma unroll
                for (int kk = 0; kk < 4; ++kk) {
                    bh[kk] = *(const s16x8*)(bp + kk * 32);
                    bl[kk] = *(const s16x8*)(lp + kk * 32);
                }
#pragma unroll
                for (int kk = 0; kk < 4; ++kk) {
                    acc[tile] = __builtin_amdgcn_mfma_f32_16x16x32_bf16(ah[kk], bh[kk], acc[tile], 0, 0, 0);
                    acc[tile] = __builtin_amdgcn_mfma_f32_16x16x32_bf16(al[kk], bh[kk], acc[tile], 0, 0, 0);
                    acc[tile] = __builtin_amdgcn_mfma_f32_16x16x32_bf16(ah[kk], bl[kk], acc[tile], 0, 0, 0);
                }
            }
        }
    }

    const int hr = h0 + wid;
#pragma unroll
    for (int tile = 0; tile < 2; ++tile) {
        int ch = tile * 16 + i;
#pragma unroll
        for (int reg = 0; reg < 4; ++reg) {
            int pxo = (lane >> 4) * 4 + reg;
            int p = hr * Ww + w0 + pxo;
            float v = acc[tile][reg];
            if (ch < 18) {
                int k = ch >> 1;
                v += b_off[ch];
                if (ch & 1) dx_o[(size_t)(b * 9 + k) * HW + p] = v;
                else        dy_o[(size_t)(b * 9 + k) * HW + p] = v;
            } else if (ch < 27) {
                int k = ch - 18;
                v += b_mask[k];
                mk_o[(size_t)(b * 9 + k) * HW + p] = 1.f / (1.f + expf(-v));
            }
        }
    }
}

// ---------------------------------------------------------------------------
// Kernel C: main deformable conv. vs r5 (186 us):
//  - A-fragments built DIRECTLY in registers: lane gathers its own pixel
//    (pm + (lane&15)) at its own 8-channel slice ((lane>>4)*8) for 4 corners
//    and blends straight into afr[kk]. val_lds + idx/wgt tables DELETED.
//  - per-lane setup (dy/dx/mk loads are one 64B line per quarter-wave);
//    no setup phase, no setup barrier.
//  - w_lds staging kept EXACTLY as r5 (B-from-global was r6's regression).
//  - 2 barriers per k: [setup+gather-issue+stage] B [blend+MFMA] B.
// Numerically identical to r5 (same blend order, f2bf, MFMA sequence).
// ---------------------------------------------------------------------------
__global__ __launch_bounds__(256) void dconv_main(
    const short* __restrict__ xT,    // [b][hw][c] bf16
    const short* __restrict__ wb,    // [k][o][c] bf16
    const float* __restrict__ bias,
    const float* __restrict__ dy_i, const float* __restrict__ dx_i,
    const float* __restrict__ mk_i,
    float* __restrict__ out)
{
    __shared__ short w_lds[128 * 128];   // 32 KB, byte ^= (o&7)<<4

    // XCD-chunked swizzle: 1600 blocks = 8 XCDs x 200 contiguous (b,tile).
    const int g = blockIdx.x;
    const int orig = (g & 7) * 200 + (g >> 3);
    const int b = orig / 400;
    const int p0 = (orig % 400) * 64;

    const int t = threadIdx.x;
    const int lane = t & 63;
    const int wid = t >> 6;
    const int pm = wid * 16;             // wave's pixel base

    const int myPx = pm + (lane & 15);   // this lane's A-row pixel
    const int p = p0 + myPx;
    const int h = p / Ww, w = p % Ww;
    const int kb8 = (lane >> 4) * 8;     // this lane's channel slice base

    const short* xbase = xT + (size_t)b * HW * Cc + kb8;

    f32x4 acc[8];
#pragma unroll
    for (int i = 0; i < 8; ++i) acc[i] = (f32x4){0.f, 0.f, 0.f, 0.f};

    for (int k = 0; k < Kk; ++k) {
        // ---- 1. per-lane bilinear setup (no LDS, no barrier) ----
        size_t obase = (size_t)(b * 9 + k) * HW + p;
        float dyv = dy_i[obase], dxv = dx_i[obase], m = mk_i[obase];
        float py  = (float)(h + (k / 3) - 1) + dyv;
        float pxf = (float)(w + (k % 3) - 1) + dxv;
        float y0f = floorf(py), x0f = floorf(pxf);
        float ly = py - y0f, lx = pxf - x0f;
        int y0 = (int)y0f, x0 = (int)x0f;
        int   idxc[4];
        float wg[4];
#pragma unroll
        for (int cr = 0; cr < 4; ++cr) {
            int iy = y0 + (cr >> 1), ix = x0 + (cr & 1);
            bool ok = ((unsigned)iy < (unsigned)Hh) && ((unsigned)ix < (unsigned)Ww);
            float wy = (cr >> 1) ? ly : (1.f - ly);
            float wx = (cr & 1) ? lx : (1.f - lx);
            int cy = min(max(iy, 0), Hh - 1);
            int cx = min(max(ix, 0), Ww - 1);
            idxc[cr] = cy * Ww + cx;
            wg[cr] = ok ? (wy * wx * m) : 0.f;
        }

        // ---- 2. issue 16 independent gather loads (hide under staging) ----
        s16x8 G[16];
#pragma unroll
        for (int cr = 0; cr < 4; ++cr) {
            const short* src = xbase + (size_t)idxc[cr] * Cc;
#pragma unroll
            for (int kk = 0; kk < 4; ++kk)
                G[cr * 4 + kk] = *(const s16x8*)(src + kk * 32);
        }

        // ---- 3. stage weights for this k (all threads, same as r5) ----
        {
            const int4* src = (const int4*)(wb + (size_t)k * 128 * 128);
#pragma unroll
            for (int i = 0; i < 8; ++i) {
                int ci = i * 256 + t;            // 16B chunk id, 0..2047
                int o = ci >> 4;                 // 16 chunks per o-row
                int byte = (ci << 4) ^ ((o & 7) << 4);
                *(int4*)((char*)w_lds + byte) = src[ci];
            }
        }
        __syncthreads();

        // ---- 4. blend corners -> A fragments (pure registers) ----
        s16x8 afr[4];
#pragma unroll
        for (int kk = 0; kk < 4; ++kk) {
#pragma unroll
            for (int j = 0; j < 8; ++j) {
                float s = wg[0] * bf2f(G[0 * 4 + kk][j])
                        + wg[1] * bf2f(G[1 * 4 + kk][j])
                        + wg[2] * bf2f(G[2 * 4 + kk][j])
                        + wg[3] * bf2f(G[3 * 4 + kk][j]);
                afr[kk][j] = f2bf(s);
            }
        }

        // ---- 5. MFMA: A in regs, B from w_lds ----
        {
            const int orow = lane & 15;
#pragma unroll
            for (int ot = 0; ot < 8; ++ot) {
                int o = ot * 16 + orow;
#pragma unroll
                for (int kk = 0; kk < 4; ++kk) {
                    int byte = (o * 256 + (kk * 32 + kb8) * 2) ^ ((o & 7) << 4);
                    s16x8 bfr = *(const s16x8*)((char*)w_lds + byte);
                    acc[ot] = __builtin_amdgcn_mfma_f32_16x16x32_bf16(afr[kk], bfr, acc[ot], 0, 0, 0);
                }
            }
        }
        __syncthreads();   // WAR: w_lds reads done before next k's staging
    }

    // ---- epilogue: D layout col=lane&15 (o), row=(lane>>4)*4+reg (px) ----
#pragma unroll
    for (int ot = 0; ot < 8; ++ot) {
        int o = ot * 16 + (lane & 15);
        float bo = bias[o];
        float4 r;
        r.x = acc[ot][0] + bo;
        r.y = acc[ot][1] + bo;
        r.z = acc[ot][2] + bo;
        r.w = acc[ot][3] + bo;
        *(float4*)(out + ((size_t)(b * On + o)) * HW + p0 + pm + (lane >> 4) * 4) = r;
    }
}

// ---------------------------------------------------------------------------
extern "C" void kernel_launch(void* const* d_in, const int* in_sizes, int n_in,
                              void* d_out, int out_size, void* d_ws, size_t ws_size,
                              hipStream_t stream) {
    const float* x      = (const float*)d_in[0];
    const float* w_off  = (const float*)d_in[1];
    const float* b_off  = (const float*)d_in[2];
    const float* w_mask = (const float*)d_in[3];
    const float* b_mask = (const float*)d_in[4];
    const float* wt     = (const float*)d_in[5];
    const float* bias   = (const float*)d_in[6];
    float* out = (float*)d_out;

    short* xT  = (short*)d_ws;                      // B*HW*C bf16 hi
    short* xLo = xT + (size_t)Bn * HW * Cc;         // B*HW*C bf16 lo
    short* wb  = xLo + (size_t)Bn * HW * Cc;        // K*O*C bf16
    short* wofm_h = wb + Kk * On * Cc;
    short* wofm_l = wofm_h + Kk * 32 * Cc;
    float* dy = (float*)(wofm_l + Kk * 32 * Cc);
    float* dx = dy + (size_t)Bn * 9 * HW;
    float* mk = dx + (size_t)Bn * 9 * HW;

    to_nhwc<<<dim3(HW / 64, Bn), 256, 0, stream>>>(x, xT, xLo);
    prep_w<<<(Kk * On * Cc + 255) / 256, 256, 0, stream>>>(wt, wb);
    prep_wofm<<<(Kk * 32 * Cc + 255) / 256, 256, 0, stream>>>(w_off, w_mask, wofm_h, wofm_l);
    offmask_mfma<<<1600, 256, 0, stream>>>(
        xT, xLo, wofm_h, wofm_l, b_off, b_mask, dy, dx, mk);
    dconv_main<<<1600, 256, 0, stream>>>(
        xT, wb, bias, dy, dx, mk, out);
}

// Round 8
// 318.132 us; speedup vs baseline: 1.5057x; 1.0979x over previous
//
#include <hip/hip_runtime.h>
#include <math.h>

constexpr int Bn = 4, Cc = 128, On = 128, Hh = 160, Ww = 160, Kk = 9;
constexpr int HW = Hh * Ww;          // 25600

typedef __attribute__((ext_vector_type(8))) short s16x8;
typedef __attribute__((ext_vector_type(4))) float f32x4;

__device__ inline float bf2f(short s) {
    union { float f; unsigned u; } v;
    v.u = ((unsigned)(unsigned short)s) << 16;
    return v.f;
}
__device__ inline short f2bf(float f) {
    union { float f; unsigned u; } v;
    v.f = f;
    unsigned r = v.u + 0x7fffu + ((v.u >> 16) & 1u);   // RNE
    return (short)(r >> 16);
}

// ---------------------------------------------------------------------------
// Kernel A1: x (NCHW f32) -> xT (NHWC bf16 hi) + xLo (NHWC bf16 lo).
// ---------------------------------------------------------------------------
__global__ __launch_bounds__(256) void to_nhwc(const float* __restrict__ x,
                                               short* __restrict__ xT,
                                               short* __restrict__ xLo) {
    __shared__ float tile[128][65];
    const int t = threadIdx.x;
    const int p0 = blockIdx.x * 64;
    const int b = blockIdx.y;
#pragma unroll
    for (int i = 0; i < 32; ++i) {
        int c = i * 4 + (t >> 6);
        tile[c][t & 63] = x[((size_t)b * Cc + c) * HW + p0 + (t & 63)];
    }
    __syncthreads();
    const int px = t >> 2, cq = t & 3;
    short* dsth = xT  + ((size_t)(b * HW) + p0 + px) * Cc;
    short* dstl = xLo + ((size_t)(b * HW) + p0 + px) * Cc;
#pragma unroll
    for (int j = 0; j < 8; ++j) {
        int c0 = cq * 4 + j * 16;
        short4 vh, vl;
        float f0 = tile[c0 + 0][px], f1 = tile[c0 + 1][px];
        float f2 = tile[c0 + 2][px], f3 = tile[c0 + 3][px];
        vh.x = f2bf(f0); vh.y = f2bf(f1); vh.z = f2bf(f2); vh.w = f2bf(f3);
        vl.x = f2bf(f0 - bf2f(vh.x));
        vl.y = f2bf(f1 - bf2f(vh.y));
        vl.z = f2bf(f2 - bf2f(vh.z));
        vl.w = f2bf(f3 - bf2f(vh.w));
        *(short4*)(dsth + c0) = vh;
        *(short4*)(dstl + c0) = vl;
    }
}

// ---------------------------------------------------------------------------
// Kernel A2: wt (O,C,3,3) f32 -> wb[k][o][c] bf16
// ---------------------------------------------------------------------------
__global__ void prep_w(const float* __restrict__ wt, short* __restrict__ wb) {
    int idx = blockIdx.x * 256 + threadIdx.x;     // K*O*C = 147456
    if (idx >= Kk * On * Cc) return;
    int c = idx & 127;
    int o = (idx >> 7) & 127;
    int k = idx >> 14;
    wb[idx] = f2bf(wt[(o * Cc + c) * 9 + k]);
}

// ---------------------------------------------------------------------------
// Kernel A3: offset/mask weights -> wofm_{hi,lo}[k][ch32][c].
// ---------------------------------------------------------------------------
__global__ void prep_wofm(const float* __restrict__ w_off,
                          const float* __restrict__ w_mask,
                          short* __restrict__ wh, short* __restrict__ wl) {
    int idx = blockIdx.x * 256 + threadIdx.x;     // 9*32*128 = 36864
    if (idx >= Kk * 32 * Cc) return;
    int c = idx & 127;
    int ch = (idx >> 7) & 31;
    int k = idx >> 12;
    float v = 0.f;
    if (ch < 18)      v = w_off[(ch * Cc + c) * 9 + k];
    else if (ch < 27) v = w_mask[((ch - 18) * Cc + c) * 9 + k];
    short hi = f2bf(v);
    wh[idx] = hi;
    wl[idx] = f2bf(v - bf2f(hi));
}

// ---------------------------------------------------------------------------
// Kernel B: offset/mask conv via MFMA, hi/lo split. r5-proven LDS-staged
// halo (zero-filled OOB) + ONE delta: register double-buffered B fragments
// across the fully-unrolled 9-tap loop (tap k+1's 16 global B-loads issue
// before tap k's MFMAs -> L2 latency hides under MFMA + LDS A-reads).
// Grid: flat 1600, XCD-chunked swizzle.
// ---------------------------------------------------------------------------
__global__ __launch_bounds__(256) void offmask_mfma(
    const short* __restrict__ xT, const short* __restrict__ xLo,
    const short* __restrict__ wh, const short* __restrict__ wl,
    const float* __restrict__ b_off, const float* __restrict__ b_mask,
    float* __restrict__ dy_o, float* __restrict__ dx_o, float* __restrict__ mk_o)
{
    __shared__ short a_hi[6][2304];   // [slot][18px * 128c], row stride 256 B
    __shared__ short a_lo[6][2304];

    const int g = blockIdx.x;
    const int orig = (g & 7) * 200 + (g >> 3);
    const int b  = orig / 400;
    const int rem = orig % 400;
    const int h0 = (rem / 10) * 4;
    const int w0 = (rem % 10) * 16;

    const int t = threadIdx.x;

    // ---- stage 6 source rows (h0-1 .. h0+4), cols w0-1 .. w0+16 ----
    const short* xh_b = xT  + (size_t)b * HW * Cc;
    const short* xl_b = xLo + (size_t)b * HW * Cc;
#pragma unroll
    for (int j = 0; j < 14; ++j) {
        int ci = j * 256 + t;
        if (ci < 3456) {
            int slot = ci / 576;
            int rem2 = ci % 576;
            int isLo = rem2 >= 288;
            int cj   = isLo ? rem2 - 288 : rem2;
            int pxl  = cj >> 4;
            int ck   = cj & 15;
            int r   = h0 - 1 + slot;
            int col = w0 - 1 + pxl;
            int4 v = make_int4(0, 0, 0, 0);
            if ((unsigned)r < (unsigned)Hh && (unsigned)col < (unsigned)Ww) {
                const short* src = (isLo ? xl_b : xh_b) +
                                   ((size_t)(r * Ww + col)) * Cc + ck * 8;
                v = *(const int4*)src;
            }
            int byte = (pxl * 256 + ck * 16) ^ ((pxl & 7) << 4);
            *(int4*)((char*)(isLo ? a_lo[slot] : a_hi[slot]) + byte) = v;
        }
    }
    __syncthreads();

    const int lane = t & 63, wid = t >> 6;
    const int i  = lane & 15;
    const int kb = (lane >> 4) * 8;

    f32x4 acc[2];
    acc[0] = (f32x4){0.f, 0.f, 0.f, 0.f};
    acc[1] = (f32x4){0.f, 0.f, 0.f, 0.f};

    // B double buffer: [buf][tile][kk], all indices compile-time under unroll
    s16x8 bh[2][2][4], bl[2][2][4];

    // prefetch tap 0
#pragma unroll
    for (int tile = 0; tile < 2; ++tile) {
        const short* bp = wh + ((size_t)(tile * 16 + i)) * Cc + kb;
        const short* lp = wl + ((size_t)(tile * 16 + i)) * Cc + kb;
#pragma unroll
        for (int kk = 0; kk < 4; ++kk) {
            bh[0][tile][kk] = *(const s16x8*)(bp + kk * 32);
            bl[0][tile][kk] = *(const s16x8*)(lp + kk * 32);
        }
    }

#pragma unroll
    for (int k = 0; k < Kk; ++k) {
        const int cur = k & 1, nxt = cur ^ 1;
        // ---- issue next tap's B loads before consuming current ----
        if (k < Kk - 1) {
            const int kn = k + 1;
#pragma unroll
            for (int tile = 0; tile < 2; ++tile) {
                const short* bp = wh + ((size_t)(kn * 32 + tile * 16 + i)) * Cc + kb;
                const short* lp = wl + ((size_t)(kn * 32 + tile * 16 + i)) * Cc + kb;
#pragma unroll
                for (int kk = 0; kk < 4; ++kk) {
                    bh[nxt][tile][kk] = *(const s16x8*)(bp + kk * 32);
                    bl[nxt][tile][kk] = *(const s16x8*)(lp + kk * 32);
                }
            }
        }
        // ---- A fragments from LDS ----
        const int ky = k / 3, kxi = k % 3;
        const int slot = wid + ky;
        const int pxl = i + kxi;
        s16x8 ah[4], al[4];
#pragma unroll
        for (int kk = 0; kk < 4; ++kk) {
            int byte = (pxl * 256 + (kk * 32 + kb) * 2) ^ ((pxl & 7) << 4);
            ah[kk] = *(const s16x8*)((char*)a_hi[slot] + byte);
            al[kk] = *(const s16x8*)((char*)a_lo[slot] + byte);
        }
        // ---- MFMA (same op order as r5: ah*bh, al*bh, ah*bl) ----
#pragma unroll
        for (int tile = 0; tile < 2; ++tile) {
#pragma unroll
            for (int kk = 0; kk < 4; ++kk) {
                acc[tile] = __builtin_amdgcn_mfma_f32_16x16x32_bf16(ah[kk], bh[cur][tile][kk], acc[tile], 0, 0, 0);
                acc[tile] = __builtin_amdgcn_mfma_f32_16x16x32_bf16(al[kk], bh[cur][tile][kk], acc[tile], 0, 0, 0);
                acc[tile] = __builtin_amdgcn_mfma_f32_16x16x32_bf16(ah[kk], bl[cur][tile][kk], acc[tile], 0, 0, 0);
            }
        }
    }

    // ---- epilogue: D col=lane&15 -> ch, row=(lane>>4)*4+reg -> px ----
    const int hr = h0 + wid;
#pragma unroll
    for (int tile = 0; tile < 2; ++tile) {
        int ch = tile * 16 + i;
#pragma unroll
        for (int reg = 0; reg < 4; ++reg) {
            int pxo = (lane >> 4) * 4 + reg;
            int p = hr * Ww + w0 + pxo;
            float v = acc[tile][reg];
            if (ch < 18) {
                int k = ch >> 1;
                v += b_off[ch];
                if (ch & 1) dx_o[(size_t)(b * 9 + k) * HW + p] = v;
                else        dy_o[(size_t)(b * 9 + k) * HW + p] = v;
            } else if (ch < 27) {
                int k = ch - 18;
                v += b_mask[k];
                mk_o[(size_t)(b * 9 + k) * HW + p] = 1.f / (1.f + expf(-v));
            }
        }
    }
}

// ---------------------------------------------------------------------------
// Kernel C: main deformable conv (UNCHANGED from round 7):
// per-lane register-direct A gather/blend + w_lds staged B, 2 barriers/k,
// XCD-chunked swizzle.
// ---------------------------------------------------------------------------
__global__ __launch_bounds__(256) void dconv_main(
    const short* __restrict__ xT,    // [b][hw][c] bf16
    const short* __restrict__ wb,    // [k][o][c] bf16
    const float* __restrict__ bias,
    const float* __restrict__ dy_i, const float* __restrict__ dx_i,
    const float* __restrict__ mk_i,
    float* __restrict__ out)
{
    __shared__ short w_lds[128 * 128];   // 32 KB, byte ^= (o&7)<<4

    const int g = blockIdx.x;
    const int orig = (g & 7) * 200 + (g >> 3);
    const int b = orig / 400;
    const int p0 = (orig % 400) * 64;

    const int t = threadIdx.x;
    const int lane = t & 63;
    const int wid = t >> 6;
    const int pm = wid * 16;             // wave's pixel base

    const int myPx = pm + (lane & 15);   // this lane's A-row pixel
    const int p = p0 + myPx;
    const int h = p / Ww, w = p % Ww;
    const int kb8 = (lane >> 4) * 8;     // this lane's channel slice base

    const short* xbase = xT + (size_t)b * HW * Cc + kb8;

    f32x4 acc[8];
#pragma unroll
    for (int i = 0; i < 8; ++i) acc[i] = (f32x4){0.f, 0.f, 0.f, 0.f};

    for (int k = 0; k < Kk; ++k) {
        // ---- 1. per-lane bilinear setup (no LDS, no barrier) ----
        size_t obase = (size_t)(b * 9 + k) * HW + p;
        float dyv = dy_i[obase], dxv = dx_i[obase], m = mk_i[obase];
        float py  = (float)(h + (k / 3) - 1) + dyv;
        float pxf = (float)(w + (k % 3) - 1) + dxv;
        float y0f = floorf(py), x0f = floorf(pxf);
        float ly = py - y0f, lx = pxf - x0f;
        int y0 = (int)y0f, x0 = (int)x0f;
        int   idxc[4];
        float wg[4];
#pragma unroll
        for (int cr = 0; cr < 4; ++cr) {
            int iy = y0 + (cr >> 1), ix = x0 + (cr & 1);
            bool ok = ((unsigned)iy < (unsigned)Hh) && ((unsigned)ix < (unsigned)Ww);
            float wy = (cr >> 1) ? ly : (1.f - ly);
            float wx = (cr & 1) ? lx : (1.f - lx);
            int cy = min(max(iy, 0), Hh - 1);
            int cx = min(max(ix, 0), Ww - 1);
            idxc[cr] = cy * Ww + cx;
            wg[cr] = ok ? (wy * wx * m) : 0.f;
        }

        // ---- 2. issue 16 independent gather loads (hide under staging) ----
        s16x8 G[16];
#pragma unroll
        for (int cr = 0; cr < 4; ++cr) {
            const short* src = xbase + (size_t)idxc[cr] * Cc;
#pragma unroll
            for (int kk = 0; kk < 4; ++kk)
                G[cr * 4 + kk] = *(const s16x8*)(src + kk * 32);
        }

        // ---- 3. stage weights for this k (all threads) ----
        {
            const int4* src = (const int4*)(wb + (size_t)k * 128 * 128);
#pragma unroll
            for (int i = 0; i < 8; ++i) {
                int ci = i * 256 + t;            // 16B chunk id, 0..2047
                int o = ci >> 4;                 // 16 chunks per o-row
                int byte = (ci << 4) ^ ((o & 7) << 4);
                *(int4*)((char*)w_lds + byte) = src[ci];
            }
        }
        __syncthreads();

        // ---- 4. blend corners -> A fragments (pure registers) ----
        s16x8 afr[4];
#pragma unroll
        for (int kk = 0; kk < 4; ++kk) {
#pragma unroll
            for (int j = 0; j < 8; ++j) {
                float s = wg[0] * bf2f(G[0 * 4 + kk][j])
                        + wg[1] * bf2f(G[1 * 4 + kk][j])
                        + wg[2] * bf2f(G[2 * 4 + kk][j])
                        + wg[3] * bf2f(G[3 * 4 + kk][j]);
                afr[kk][j] = f2bf(s);
            }
        }

        // ---- 5. MFMA: A in regs, B from w_lds ----
        {
            const int orow = lane & 15;
#pragma unroll
            for (int ot = 0; ot < 8; ++ot) {
                int o = ot * 16 + orow;
#pragma unroll
                for (int kk = 0; kk < 4; ++kk) {
                    int byte = (o * 256 + (kk * 32 + kb8) * 2) ^ ((o & 7) << 4);
                    s16x8 bfr = *(const s16x8*)((char*)w_lds + byte);
                    acc[ot] = __builtin_amdgcn_mfma_f32_16x16x32_bf16(afr[kk], bfr, acc[ot], 0, 0, 0);
                }
            }
        }
        __syncthreads();   // WAR: w_lds reads done before next k's staging
    }

    // ---- epilogue: D layout col=lane&15 (o), row=(lane>>4)*4+reg (px) ----
#pragma unroll
    for (int ot = 0; ot < 8; ++ot) {
        int o = ot * 16 + (lane & 15);
        float bo = bias[o];
        float4 r;
        r.x = acc[ot][0] + bo;
        r.y = acc[ot][1] + bo;
        r.z = acc[ot][2] + bo;
        r.w = acc[ot][3] + bo;
        *(float4*)(out + ((size_t)(b * On + o)) * HW + p0 + pm + (lane >> 4) * 4) = r;
    }
}

// ---------------------------------------------------------------------------
extern "C" void kernel_launch(void* const* d_in, const int* in_sizes, int n_in,
                              void* d_out, int out_size, void* d_ws, size_t ws_size,
                              hipStream_t stream) {
    const float* x      = (const float*)d_in[0];
    const float* w_off  = (const float*)d_in[1];
    const float* b_off  = (const float*)d_in[2];
    const float* w_mask = (const float*)d_in[3];
    const float* b_mask = (const float*)d_in[4];
    const float* wt     = (const float*)d_in[5];
    const float* bias   = (const float*)d_in[6];
    float* out = (float*)d_out;

    short* xT  = (short*)d_ws;                      // B*HW*C bf16 hi
    short* xLo = xT + (size_t)Bn * HW * Cc;         // B*HW*C bf16 lo
    short* wb  = xLo + (size_t)Bn * HW * Cc;        // K*O*C bf16
    short* wofm_h = wb + Kk * On * Cc;
    short* wofm_l = wofm_h + Kk * 32 * Cc;
    float* dy = (float*)(wofm_l + Kk * 32 * Cc);
    float* dx = dy + (size_t)Bn * 9 * HW;
    float* mk = dx + (size_t)Bn * 9 * HW;

    to_nhwc<<<dim3(HW / 64, Bn), 256, 0, stream>>>(x, xT, xLo);
    prep_w<<<(Kk * On * Cc + 255) / 256, 256, 0, stream>>>(wt, wb);
    prep_wofm<<<(Kk * 32 * Cc + 255) / 256, 256, 0, stream>>>(w_off, w_mask, wofm_h, wofm_l);
    offmask_mfma<<<1600, 256, 0, stream>>>(
        xT, xLo, wofm_h, wofm_l, b_off, b_mask, dy, dx, mk);
    dconv_main<<<1600, 256, 0, stream>>>(
        xT, wb, bias, dy, dx, mk, out);
}

// Round 9
// 307.282 us; speedup vs baseline: 1.5589x; 1.0353x over previous
//
#include <hip/hip_runtime.h>
#include <math.h>

constexpr int Bn = 4, Cc = 128, On = 128, Hh = 160, Ww = 160, Kk = 9;
constexpr int HW = Hh * Ww;          // 25600

typedef __attribute__((ext_vector_type(8))) short s16x8;
typedef __attribute__((ext_vector_type(4))) float f32x4;

__device__ inline float bf2f(short s) {
    union { float f; unsigned u; } v;
    v.u = ((unsigned)(unsigned short)s) << 16;
    return v.f;
}
__device__ inline short f2bf(float f) {
    union { float f; unsigned u; } v;
    v.f = f;
    unsigned r = v.u + 0x7fffu + ((v.u >> 16) & 1u);   // RNE
    return (short)(r >> 16);
}

// ---------------------------------------------------------------------------
// Kernel A1: x (NCHW f32) -> xT (NHWC bf16 hi) + xLo (NHWC bf16 lo).
// ---------------------------------------------------------------------------
__global__ __launch_bounds__(256) void to_nhwc(const float* __restrict__ x,
                                               short* __restrict__ xT,
                                               short* __restrict__ xLo) {
    __shared__ float tile[128][65];
    const int t = threadIdx.x;
    const int p0 = blockIdx.x * 64;
    const int b = blockIdx.y;
#pragma unroll
    for (int i = 0; i < 32; ++i) {
        int c = i * 4 + (t >> 6);
        tile[c][t & 63] = x[((size_t)b * Cc + c) * HW + p0 + (t & 63)];
    }
    __syncthreads();
    const int px = t >> 2, cq = t & 3;
    short* dsth = xT  + ((size_t)(b * HW) + p0 + px) * Cc;
    short* dstl = xLo + ((size_t)(b * HW) + p0 + px) * Cc;
#pragma unroll
    for (int j = 0; j < 8; ++j) {
        int c0 = cq * 4 + j * 16;
        short4 vh, vl;
        float f0 = tile[c0 + 0][px], f1 = tile[c0 + 1][px];
        float f2 = tile[c0 + 2][px], f3 = tile[c0 + 3][px];
        vh.x = f2bf(f0); vh.y = f2bf(f1); vh.z = f2bf(f2); vh.w = f2bf(f3);
        vl.x = f2bf(f0 - bf2f(vh.x));
        vl.y = f2bf(f1 - bf2f(vh.y));
        vl.z = f2bf(f2 - bf2f(vh.z));
        vl.w = f2bf(f3 - bf2f(vh.w));
        *(short4*)(dsth + c0) = vh;
        *(short4*)(dstl + c0) = vl;
    }
}

// ---------------------------------------------------------------------------
// Kernel A2: wt (O,C,3,3) f32 -> wb[k][o][c] bf16
// ---------------------------------------------------------------------------
__global__ void prep_w(const float* __restrict__ wt, short* __restrict__ wb) {
    int idx = blockIdx.x * 256 + threadIdx.x;     // K*O*C = 147456
    if (idx >= Kk * On * Cc) return;
    int c = idx & 127;
    int o = (idx >> 7) & 127;
    int k = idx >> 14;
    wb[idx] = f2bf(wt[(o * Cc + c) * 9 + k]);
}

// ---------------------------------------------------------------------------
// Kernel A3: offset/mask weights -> wofm_{hi,lo}[k][ch32][c].
// ---------------------------------------------------------------------------
__global__ void prep_wofm(const float* __restrict__ w_off,
                          const float* __restrict__ w_mask,
                          short* __restrict__ wh, short* __restrict__ wl) {
    int idx = blockIdx.x * 256 + threadIdx.x;     // 9*32*128 = 36864
    if (idx >= Kk * 32 * Cc) return;
    int c = idx & 127;
    int ch = (idx >> 7) & 31;
    int k = idx >> 12;
    float v = 0.f;
    if (ch < 18)      v = w_off[(ch * Cc + c) * 9 + k];
    else if (ch < 27) v = w_mask[((ch - 18) * Cc + c) * 9 + k];
    short hi = f2bf(v);
    wh[idx] = hi;
    wl[idx] = f2bf(v - bf2f(hi));
}

// ---------------------------------------------------------------------------
// Kernel B: offset/mask conv via MFMA, hi/lo split. LDS-staged halo +
// register double-buffered B fragments (unchanged from round 8 — passed).
// ---------------------------------------------------------------------------
__global__ __launch_bounds__(256) void offmask_mfma(
    const short* __restrict__ xT, const short* __restrict__ xLo,
    const short* __restrict__ wh, const short* __restrict__ wl,
    const float* __restrict__ b_off, const float* __restrict__ b_mask,
    float* __restrict__ dy_o, float* __restrict__ dx_o, float* __restrict__ mk_o)
{
    __shared__ short a_hi[6][2304];   // [slot][18px * 128c], row stride 256 B
    __shared__ short a_lo[6][2304];

    const int g = blockIdx.x;
    const int orig = (g & 7) * 200 + (g >> 3);
    const int b  = orig / 400;
    const int rem = orig % 400;
    const int h0 = (rem / 10) * 4;
    const int w0 = (rem % 10) * 16;

    const int t = threadIdx.x;

    const short* xh_b = xT  + (size_t)b * HW * Cc;
    const short* xl_b = xLo + (size_t)b * HW * Cc;
#pragma unroll
    for (int j = 0; j < 14; ++j) {
        int ci = j * 256 + t;
        if (ci < 3456) {
            int slot = ci / 576;
            int rem2 = ci % 576;
            int isLo = rem2 >= 288;
            int cj   = isLo ? rem2 - 288 : rem2;
            int pxl  = cj >> 4;
            int ck   = cj & 15;
            int r   = h0 - 1 + slot;
            int col = w0 - 1 + pxl;
            int4 v = make_int4(0, 0, 0, 0);
            if ((unsigned)r < (unsigned)Hh && (unsigned)col < (unsigned)Ww) {
                const short* src = (isLo ? xl_b : xh_b) +
                                   ((size_t)(r * Ww + col)) * Cc + ck * 8;
                v = *(const int4*)src;
            }
            int byte = (pxl * 256 + ck * 16) ^ ((pxl & 7) << 4);
            *(int4*)((char*)(isLo ? a_lo[slot] : a_hi[slot]) + byte) = v;
        }
    }
    __syncthreads();

    const int lane = t & 63, wid = t >> 6;
    const int i  = lane & 15;
    const int kb = (lane >> 4) * 8;

    f32x4 acc[2];
    acc[0] = (f32x4){0.f, 0.f, 0.f, 0.f};
    acc[1] = (f32x4){0.f, 0.f, 0.f, 0.f};

    s16x8 bh[2][2][4], bl[2][2][4];

#pragma unroll
    for (int tile = 0; tile < 2; ++tile) {
        const short* bp = wh + ((size_t)(tile * 16 + i)) * Cc + kb;
        const short* lp = wl + ((size_t)(tile * 16 + i)) * Cc + kb;
#pragma unroll
        for (int kk = 0; kk < 4; ++kk) {
            bh[0][tile][kk] = *(const s16x8*)(bp + kk * 32);
            bl[0][tile][kk] = *(const s16x8*)(lp + kk * 32);
        }
    }

#pragma unroll
    for (int k = 0; k < Kk; ++k) {
        const int cur = k & 1, nxt = cur ^ 1;
        if (k < Kk - 1) {
            const int kn = k + 1;
#pragma unroll
            for (int tile = 0; tile < 2; ++tile) {
                const short* bp = wh + ((size_t)(kn * 32 + tile * 16 + i)) * Cc + kb;
                const short* lp = wl + ((size_t)(kn * 32 + tile * 16 + i)) * Cc + kb;
#pragma unroll
                for (int kk = 0; kk < 4; ++kk) {
                    bh[nxt][tile][kk] = *(const s16x8*)(bp + kk * 32);
                    bl[nxt][tile][kk] = *(const s16x8*)(lp + kk * 32);
                }
            }
        }
        const int ky = k / 3, kxi = k % 3;
        const int slot = wid + ky;
        const int pxl = i + kxi;
        s16x8 ah[4], al[4];
#pragma unroll
        for (int kk = 0; kk < 4; ++kk) {
            int byte = (pxl * 256 + (kk * 32 + kb) * 2) ^ ((pxl & 7) << 4);
            ah[kk] = *(const s16x8*)((char*)a_hi[slot] + byte);
            al[kk] = *(const s16x8*)((char*)a_lo[slot] + byte);
        }
#pragma unroll
        for (int tile = 0; tile < 2; ++tile) {
#pragma unroll
            for (int kk = 0; kk < 4; ++kk) {
                acc[tile] = __builtin_amdgcn_mfma_f32_16x16x32_bf16(ah[kk], bh[cur][tile][kk], acc[tile], 0, 0, 0);
                acc[tile] = __builtin_amdgcn_mfma_f32_16x16x32_bf16(al[kk], bh[cur][tile][kk], acc[tile], 0, 0, 0);
                acc[tile] = __builtin_amdgcn_mfma_f32_16x16x32_bf16(ah[kk], bl[cur][tile][kk], acc[tile], 0, 0, 0);
            }
        }
    }

    const int hr = h0 + wid;
#pragma unroll
    for (int tile = 0; tile < 2; ++tile) {
        int ch = tile * 16 + i;
#pragma unroll
        for (int reg = 0; reg < 4; ++reg) {
            int pxo = (lane >> 4) * 4 + reg;
            int p = hr * Ww + w0 + pxo;
            float v = acc[tile][reg];
            if (ch < 18) {
                int k = ch >> 1;
                v += b_off[ch];
                if (ch & 1) dx_o[(size_t)(b * 9 + k) * HW + p] = v;
                else        dy_o[(size_t)(b * 9 + k) * HW + p] = v;
            } else if (ch < 27) {
                int k = ch - 18;
                v += b_mask[k];
                mk_o[(size_t)(b * 9 + k) * HW + p] = 1.f / (1.f + expf(-v));
            }
        }
    }
}

// ---------------------------------------------------------------------------
// Kernel C: main deformable conv — r8 body, ONE structural edit:
// software pipeline with double-buffered w_lds, ONE barrier per k.
// Per k: [om-loads(k+1)] blend G(k) -> [setup+gathers(k+1)] -> MFMA(k)
//        from w_lds[k&1] -> stage w(k+1) into w_lds[(k+1)&1] -> barrier.
// All prefetch latencies hide under blend(~700cy)+MFMA; WAR on the staging
// buffer is protected by the previous iteration's barrier. Loop fully
// unrolled -> static register indices. Numerics identical to r8.
// ---------------------------------------------------------------------------
__global__ __launch_bounds__(256) void dconv_main(
    const short* __restrict__ xT,    // [b][hw][c] bf16
    const short* __restrict__ wb,    // [k][o][c] bf16
    const float* __restrict__ bias,
    const float* __restrict__ dy_i, const float* __restrict__ dx_i,
    const float* __restrict__ mk_i,
    float* __restrict__ out)
{
    __shared__ short w_lds[2][128 * 128];   // 2 x 32 KB, byte ^= (o&7)<<4

    const int g = blockIdx.x;
    const int orig = (g & 7) * 200 + (g >> 3);
    const int b = orig / 400;
    const int p0 = (orig % 400) * 64;

    const int t = threadIdx.x;
    const int lane = t & 63;
    const int wid = t >> 6;
    const int pm = wid * 16;             // wave's pixel base

    const int myPx = pm + (lane & 15);   // this lane's A-row pixel
    const int p = p0 + myPx;
    const int h = p / Ww, w = p % Ww;
    const int kb8 = (lane >> 4) * 8;     // this lane's channel slice base

    const short* xbase = xT + (size_t)b * HW * Cc + kb8;

    f32x4 acc[8];
#pragma unroll
    for (int i = 0; i < 8; ++i) acc[i] = (f32x4){0.f, 0.f, 0.f, 0.f};

    float wg[4];
    int   idxc[4];
    s16x8 G[16];

#define SETUP(kq, dyv, dxv, mv)                                                \
    {                                                                          \
        float py  = (float)(h + ((kq) / 3) - 1) + (dyv);                       \
        float pxf = (float)(w + ((kq) % 3) - 1) + (dxv);                       \
        float y0f = floorf(py), x0f = floorf(pxf);                             \
        float ly = py - y0f, lx = pxf - x0f;                                   \
        int y0 = (int)y0f, x0 = (int)x0f;                                      \
        _Pragma("unroll")                                                      \
        for (int cr = 0; cr < 4; ++cr) {                                       \
            int iy = y0 + (cr >> 1), ix = x0 + (cr & 1);                       \
            bool ok = ((unsigned)iy < (unsigned)Hh) && ((unsigned)ix < (unsigned)Ww); \
            float wy = (cr >> 1) ? ly : (1.f - ly);                            \
            float wx = (cr & 1) ? lx : (1.f - lx);                             \
            int cy = min(max(iy, 0), Hh - 1);                                  \
            int cx = min(max(ix, 0), Ww - 1);                                  \
            idxc[cr] = cy * Ww + cx;                                           \
            wg[cr] = ok ? (wy * wx * (mv)) : 0.f;                              \
        }                                                                      \
    }

#define ISSUEG                                                                 \
    {                                                                          \
        _Pragma("unroll")                                                      \
        for (int cr = 0; cr < 4; ++cr) {                                       \
            const short* src = xbase + (size_t)idxc[cr] * Cc;                  \
            _Pragma("unroll")                                                  \
            for (int kk = 0; kk < 4; ++kk)                                     \
                G[cr * 4 + kk] = *(const s16x8*)(src + kk * 32);               \
        }                                                                      \
    }

#define STAGE(kq, bufIdx)                                                      \
    {                                                                          \
        const int4* src = (const int4*)(wb + (size_t)(kq) * 128 * 128);        \
        _Pragma("unroll")                                                      \
        for (int i2 = 0; i2 < 8; ++i2) {                                       \
            int ci = i2 * 256 + t;                                             \
            int o = ci >> 4;                                                   \
            int byte = (ci << 4) ^ ((o & 7) << 4);                             \
            *(int4*)((char*)w_lds[bufIdx] + byte) = src[ci];                   \
        }                                                                      \
    }

    // ---- prologue: tap 0 fully prepared ----
    {
        size_t ob = (size_t)(b * 9 + 0) * HW + p;
        float dyv = dy_i[ob], dxv = dx_i[ob], mv = mk_i[ob];
        SETUP(0, dyv, dxv, mv);
    }
    ISSUEG;
    STAGE(0, 0);
    __syncthreads();

#pragma unroll
    for (int k = 0; k < Kk; ++k) {
        // ---- issue next tap's offset/mask loads early (consumed post-blend)
        float dyn = 0.f, dxn = 0.f, mn = 0.f;
        if (k < Kk - 1) {
            size_t ob = (size_t)(b * 9 + k + 1) * HW + p;
            dyn = dy_i[ob]; dxn = dx_i[ob]; mn = mk_i[ob];
        }

        // ---- blend corners -> A fragments (consumes G(k), wg(k)) ----
        s16x8 afr[4];
#pragma unroll
        for (int kk = 0; kk < 4; ++kk) {
#pragma unroll
            for (int j = 0; j < 8; ++j) {
                float s = wg[0] * bf2f(G[0 * 4 + kk][j])
                        + wg[1] * bf2f(G[1 * 4 + kk][j])
                        + wg[2] * bf2f(G[2 * 4 + kk][j])
                        + wg[3] * bf2f(G[3 * 4 + kk][j]);
                afr[kk][j] = f2bf(s);
            }
        }

        // ---- prefetch next tap: setup + issue 16 gathers into G ----
        if (k < Kk - 1) {
            SETUP(k + 1, dyn, dxn, mn);
            ISSUEG;
        }

        // ---- MFMA(k): A in regs, B from w_lds[k&1] ----
        {
            const int orow = lane & 15;
#pragma unroll
            for (int ot = 0; ot < 8; ++ot) {
                int o = ot * 16 + orow;
#pragma unroll
                for (int kk = 0; kk < 4; ++kk) {
                    int byte = (o * 256 + (kk * 32 + kb8) * 2) ^ ((o & 7) << 4);
                    s16x8 bfr = *(const s16x8*)((char*)w_lds[k & 1] + byte);
                    acc[ot] = __builtin_amdgcn_mfma_f32_16x16x32_bf16(afr[kk], bfr, acc[ot], 0, 0, 0);
                }
            }
        }

        // ---- stage next tap's weights into the other buffer ----
        if (k < Kk - 1) STAGE(k + 1, (k + 1) & 1);
        __syncthreads();   // w(k+1) ready; WAR for next stage; drains G loads
    }

#undef SETUP
#undef ISSUEG
#undef STAGE

    // ---- epilogue: D layout col=lane&15 (o), row=(lane>>4)*4+reg (px) ----
#pragma unroll
    for (int ot = 0; ot < 8; ++ot) {
        int o = ot * 16 + (lane & 15);
        float bo = bias[o];
        float4 r;
        r.x = acc[ot][0] + bo;
        r.y = acc[ot][1] + bo;
        r.z = acc[ot][2] + bo;
        r.w = acc[ot][3] + bo;
        *(float4*)(out + ((size_t)(b * On + o)) * HW + p0 + pm + (lane >> 4) * 4) = r;
    }
}

// ---------------------------------------------------------------------------
extern "C" void kernel_launch(void* const* d_in, const int* in_sizes, int n_in,
                              void* d_out, int out_size, void* d_ws, size_t ws_size,
                              hipStream_t stream) {
    const float* x      = (const float*)d_in[0];
    const float* w_off  = (const float*)d_in[1];
    const float* b_off  = (const float*)d_in[2];
    const float* w_mask = (const float*)d_in[3];
    const float* b_mask = (const float*)d_in[4];
    const float* wt     = (const float*)d_in[5];
    const float* bias   = (const float*)d_in[6];
    float* out = (float*)d_out;

    short* xT  = (short*)d_ws;                      // B*HW*C bf16 hi
    short* xLo = xT + (size_t)Bn * HW * Cc;         // B*HW*C bf16 lo
    short* wb  = xLo + (size_t)Bn * HW * Cc;        // K*O*C bf16
    short* wofm_h = wb + Kk * On * Cc;
    short* wofm_l = wofm_h + Kk * 32 * Cc;
    float* dy = (float*)(wofm_l + Kk * 32 * Cc);
    float* dx = dy + (size_t)Bn * 9 * HW;
    float* mk = dx + (size_t)Bn * 9 * HW;

    to_nhwc<<<dim3(HW / 64, Bn), 256, 0, stream>>>(x, xT, xLo);
    prep_w<<<(Kk * On * Cc + 255) / 256, 256, 0, stream>>>(wt, wb);
    prep_wofm<<<(Kk * 32 * Cc + 255) / 256, 256, 0, stream>>>(w_off, w_mask, wofm_h, wofm_l);
    offmask_mfma<<<1600, 256, 0, stream>>>(
        xT, xLo, wofm_h, wofm_l, b_off, b_mask, dy, dx, mk);
    dconv_main<<<1600, 256, 0, stream>>>(
        xT, wb, bias, dy, dx, mk, out);
}

// Round 10
// 306.540 us; speedup vs baseline: 1.5627x; 1.0024x over previous
//
#include <hip/hip_runtime.h>
#include <math.h>

constexpr int Bn = 4, Cc = 128, On = 128, Hh = 160, Ww = 160, Kk = 9;
constexpr int HW = Hh * Ww;          // 25600

typedef __attribute__((ext_vector_type(8))) short s16x8;
typedef __attribute__((ext_vector_type(4))) float f32x4;

__device__ inline float bf2f(short s) {
    union { float f; unsigned u; } v;
    v.u = ((unsigned)(unsigned short)s) << 16;
    return v.f;
}
__device__ inline short f2bf(float f) {
    union { float f; unsigned u; } v;
    v.f = f;
    unsigned r = v.u + 0x7fffu + ((v.u >> 16) & 1u);   // RNE
    return (short)(r >> 16);
}

// ---------------------------------------------------------------------------
// Kernel A1: x (NCHW f32) -> xT (NHWC bf16 hi) + xLo (NHWC bf16 lo).
// ---------------------------------------------------------------------------
__global__ __launch_bounds__(256) void to_nhwc(const float* __restrict__ x,
                                               short* __restrict__ xT,
                                               short* __restrict__ xLo) {
    __shared__ float tile[128][65];
    const int t = threadIdx.x;
    const int p0 = blockIdx.x * 64;
    const int b = blockIdx.y;
#pragma unroll
    for (int i = 0; i < 32; ++i) {
        int c = i * 4 + (t >> 6);
        tile[c][t & 63] = x[((size_t)b * Cc + c) * HW + p0 + (t & 63)];
    }
    __syncthreads();
    const int px = t >> 2, cq = t & 3;
    short* dsth = xT  + ((size_t)(b * HW) + p0 + px) * Cc;
    short* dstl = xLo + ((size_t)(b * HW) + p0 + px) * Cc;
#pragma unroll
    for (int j = 0; j < 8; ++j) {
        int c0 = cq * 4 + j * 16;
        short4 vh, vl;
        float f0 = tile[c0 + 0][px], f1 = tile[c0 + 1][px];
        float f2 = tile[c0 + 2][px], f3 = tile[c0 + 3][px];
        vh.x = f2bf(f0); vh.y = f2bf(f1); vh.z = f2bf(f2); vh.w = f2bf(f3);
        vl.x = f2bf(f0 - bf2f(vh.x));
        vl.y = f2bf(f1 - bf2f(vh.y));
        vl.z = f2bf(f2 - bf2f(vh.z));
        vl.w = f2bf(f3 - bf2f(vh.w));
        *(short4*)(dsth + c0) = vh;
        *(short4*)(dstl + c0) = vl;
    }
}

// ---------------------------------------------------------------------------
// Kernel A2: wt (O,C,3,3) f32 -> wb[k][o][c] bf16
// ---------------------------------------------------------------------------
__global__ void prep_w(const float* __restrict__ wt, short* __restrict__ wb) {
    int idx = blockIdx.x * 256 + threadIdx.x;     // K*O*C = 147456
    if (idx >= Kk * On * Cc) return;
    int c = idx & 127;
    int o = (idx >> 7) & 127;
    int k = idx >> 14;
    wb[idx] = f2bf(wt[(o * Cc + c) * 9 + k]);
}

// ---------------------------------------------------------------------------
// Kernel A3: offset/mask weights -> wofm_{hi,lo}[k][ch32][c].
// ---------------------------------------------------------------------------
__global__ void prep_wofm(const float* __restrict__ w_off,
                          const float* __restrict__ w_mask,
                          short* __restrict__ wh, short* __restrict__ wl) {
    int idx = blockIdx.x * 256 + threadIdx.x;     // 9*32*128 = 36864
    if (idx >= Kk * 32 * Cc) return;
    int c = idx & 127;
    int ch = (idx >> 7) & 31;
    int k = idx >> 12;
    float v = 0.f;
    if (ch < 18)      v = w_off[(ch * Cc + c) * 9 + k];
    else if (ch < 27) v = w_mask[((ch - 18) * Cc + c) * 9 + k];
    short hi = f2bf(v);
    wh[idx] = hi;
    wl[idx] = f2bf(v - bf2f(hi));
}

// ---------------------------------------------------------------------------
// Kernel B: offset/mask conv via MFMA, hi/lo split. LDS-staged halo +
// register double-buffered B fragments (unchanged from round 8 — passed).
// ---------------------------------------------------------------------------
__global__ __launch_bounds__(256) void offmask_mfma(
    const short* __restrict__ xT, const short* __restrict__ xLo,
    const short* __restrict__ wh, const short* __restrict__ wl,
    const float* __restrict__ b_off, const float* __restrict__ b_mask,
    float* __restrict__ dy_o, float* __restrict__ dx_o, float* __restrict__ mk_o)
{
    __shared__ short a_hi[6][2304];   // [slot][18px * 128c], row stride 256 B
    __shared__ short a_lo[6][2304];

    const int g = blockIdx.x;
    const int orig = (g & 7) * 200 + (g >> 3);
    const int b  = orig / 400;
    const int rem = orig % 400;
    const int h0 = (rem / 10) * 4;
    const int w0 = (rem % 10) * 16;

    const int t = threadIdx.x;

    const short* xh_b = xT  + (size_t)b * HW * Cc;
    const short* xl_b = xLo + (size_t)b * HW * Cc;
#pragma unroll
    for (int j = 0; j < 14; ++j) {
        int ci = j * 256 + t;
        if (ci < 3456) {
            int slot = ci / 576;
            int rem2 = ci % 576;
            int isLo = rem2 >= 288;
            int cj   = isLo ? rem2 - 288 : rem2;
            int pxl  = cj >> 4;
            int ck   = cj & 15;
            int r   = h0 - 1 + slot;
            int col = w0 - 1 + pxl;
            int4 v = make_int4(0, 0, 0, 0);
            if ((unsigned)r < (unsigned)Hh && (unsigned)col < (unsigned)Ww) {
                const short* src = (isLo ? xl_b : xh_b) +
                                   ((size_t)(r * Ww + col)) * Cc + ck * 8;
                v = *(const int4*)src;
            }
            int byte = (pxl * 256 + ck * 16) ^ ((pxl & 7) << 4);
            *(int4*)((char*)(isLo ? a_lo[slot] : a_hi[slot]) + byte) = v;
        }
    }
    __syncthreads();

    const int lane = t & 63, wid = t >> 6;
    const int i  = lane & 15;
    const int kb = (lane >> 4) * 8;

    f32x4 acc[2];
    acc[0] = (f32x4){0.f, 0.f, 0.f, 0.f};
    acc[1] = (f32x4){0.f, 0.f, 0.f, 0.f};

    s16x8 bh[2][2][4], bl[2][2][4];

#pragma unroll
    for (int tile = 0; tile < 2; ++tile) {
        const short* bp = wh + ((size_t)(tile * 16 + i)) * Cc + kb;
        const short* lp = wl + ((size_t)(tile * 16 + i)) * Cc + kb;
#pragma unroll
        for (int kk = 0; kk < 4; ++kk) {
            bh[0][tile][kk] = *(const s16x8*)(bp + kk * 32);
            bl[0][tile][kk] = *(const s16x8*)(lp + kk * 32);
        }
    }

#pragma unroll
    for (int k = 0; k < Kk; ++k) {
        const int cur = k & 1, nxt = cur ^ 1;
        if (k < Kk - 1) {
            const int kn = k + 1;
#pragma unroll
            for (int tile = 0; tile < 2; ++tile) {
                const short* bp = wh + ((size_t)(kn * 32 + tile * 16 + i)) * Cc + kb;
                const short* lp = wl + ((size_t)(kn * 32 + tile * 16 + i)) * Cc + kb;
#pragma unroll
                for (int kk = 0; kk < 4; ++kk) {
                    bh[nxt][tile][kk] = *(const s16x8*)(bp + kk * 32);
                    bl[nxt][tile][kk] = *(const s16x8*)(lp + kk * 32);
                }
            }
        }
        const int ky = k / 3, kxi = k % 3;
        const int slot = wid + ky;
        const int pxl = i + kxi;
        s16x8 ah[4], al[4];
#pragma unroll
        for (int kk = 0; kk < 4; ++kk) {
            int byte = (pxl * 256 + (kk * 32 + kb) * 2) ^ ((pxl & 7) << 4);
            ah[kk] = *(const s16x8*)((char*)a_hi[slot] + byte);
            al[kk] = *(const s16x8*)((char*)a_lo[slot] + byte);
        }
#pragma unroll
        for (int tile = 0; tile < 2; ++tile) {
#pragma unroll
            for (int kk = 0; kk < 4; ++kk) {
                acc[tile] = __builtin_amdgcn_mfma_f32_16x16x32_bf16(ah[kk], bh[cur][tile][kk], acc[tile], 0, 0, 0);
                acc[tile] = __builtin_amdgcn_mfma_f32_16x16x32_bf16(al[kk], bh[cur][tile][kk], acc[tile], 0, 0, 0);
                acc[tile] = __builtin_amdgcn_mfma_f32_16x16x32_bf16(ah[kk], bl[cur][tile][kk], acc[tile], 0, 0, 0);
            }
        }
    }

    const int hr = h0 + wid;
#pragma unroll
    for (int tile = 0; tile < 2; ++tile) {
        int ch = tile * 16 + i;
#pragma unroll
        for (int reg = 0; reg < 4; ++reg) {
            int pxo = (lane >> 4) * 4 + reg;
            int p = hr * Ww + w0 + pxo;
            float v = acc[tile][reg];
            if (ch < 18) {
                int k = ch >> 1;
                v += b_off[ch];
                if (ch & 1) dx_o[(size_t)(b * 9 + k) * HW + p] = v;
                else        dy_o[(size_t)(b * 9 + k) * HW + p] = v;
            } else if (ch < 27) {
                int k = ch - 18;
                v += b_mask[k];
                mk_o[(size_t)(b * 9 + k) * HW + p] = 1.f / (1.f + expf(-v));
            }
        }
    }
}

// ---------------------------------------------------------------------------
// Kernel C: main deformable conv — r9 pipeline with TWO local edits:
//  (1) T14 stage-split: weight loads for k+1 issue at the TOP of iter k
//      into Wr[8] regs; ds_writes happen AFTER MFMA(k). The barrier's
//      vmcnt drain no longer waits on fresh weight loads.
//  (2) w_lds swizzle widened (o&7)->(o&15), write+read together:
//      kills the o/o+8 + channel-group aliasing on B ds_reads.
// Sync structure (1 barrier/k), numerics: identical to r9.
// ---------------------------------------------------------------------------
__global__ __launch_bounds__(256) void dconv_main(
    const short* __restrict__ xT,    // [b][hw][c] bf16
    const short* __restrict__ wb,    // [k][o][c] bf16
    const float* __restrict__ bias,
    const float* __restrict__ dy_i, const float* __restrict__ dx_i,
    const float* __restrict__ mk_i,
    float* __restrict__ out)
{
    __shared__ short w_lds[2][128 * 128];   // 2 x 32 KB, byte ^= (o&15)<<4

    const int g = blockIdx.x;
    const int orig = (g & 7) * 200 + (g >> 3);
    const int b = orig / 400;
    const int p0 = (orig % 400) * 64;

    const int t = threadIdx.x;
    const int lane = t & 63;
    const int wid = t >> 6;
    const int pm = wid * 16;             // wave's pixel base

    const int myPx = pm + (lane & 15);   // this lane's A-row pixel
    const int p = p0 + myPx;
    const int h = p / Ww, w = p % Ww;
    const int kb8 = (lane >> 4) * 8;     // this lane's channel slice base

    const short* xbase = xT + (size_t)b * HW * Cc + kb8;

    f32x4 acc[8];
#pragma unroll
    for (int i = 0; i < 8; ++i) acc[i] = (f32x4){0.f, 0.f, 0.f, 0.f};

    float wg[4];
    int   idxc[4];
    s16x8 G[16];
    int4  Wr[8];

#define SETUP(kq, dyv, dxv, mv)                                                \
    {                                                                          \
        float py  = (float)(h + ((kq) / 3) - 1) + (dyv);                       \
        float pxf = (float)(w + ((kq) % 3) - 1) + (dxv);                       \
        float y0f = floorf(py), x0f = floorf(pxf);                             \
        float ly = py - y0f, lx = pxf - x0f;                                   \
        int y0 = (int)y0f, x0 = (int)x0f;                                      \
        _Pragma("unroll")                                                      \
        for (int cr = 0; cr < 4; ++cr) {                                       \
            int iy = y0 + (cr >> 1), ix = x0 + (cr & 1);                       \
            bool ok = ((unsigned)iy < (unsigned)Hh) && ((unsigned)ix < (unsigned)Ww); \
            float wy = (cr >> 1) ? ly : (1.f - ly);                            \
            float wx = (cr & 1) ? lx : (1.f - lx);                             \
            int cy = min(max(iy, 0), Hh - 1);                                  \
            int cx = min(max(ix, 0), Ww - 1);                                  \
            idxc[cr] = cy * Ww + cx;                                           \
            wg[cr] = ok ? (wy * wx * (mv)) : 0.f;                              \
        }                                                                      \
    }

#define ISSUEG                                                                 \
    {                                                                          \
        _Pragma("unroll")                                                      \
        for (int cr = 0; cr < 4; ++cr) {                                       \
            const short* src = xbase + (size_t)idxc[cr] * Cc;                  \
            _Pragma("unroll")                                                  \
            for (int kk = 0; kk < 4; ++kk)                                     \
                G[cr * 4 + kk] = *(const s16x8*)(src + kk * 32);               \
        }                                                                      \
    }

#define LOADW(kq)                                                              \
    {                                                                          \
        const int4* src = (const int4*)(wb + (size_t)(kq) * 128 * 128);        \
        _Pragma("unroll")                                                      \
        for (int i2 = 0; i2 < 8; ++i2) Wr[i2] = src[i2 * 256 + t];             \
    }

#define WRITEW(bufIdx)                                                         \
    {                                                                          \
        _Pragma("unroll")                                                      \
        for (int i2 = 0; i2 < 8; ++i2) {                                       \
            int ci = i2 * 256 + t;                                             \
            int o = ci >> 4;                                                   \
            int byte = (ci << 4) ^ ((o & 15) << 4);                            \
            *(int4*)((char*)w_lds[bufIdx] + byte) = Wr[i2];                    \
        }                                                                      \
    }

    // ---- prologue: tap 0 fully prepared ----
    LOADW(0);
    {
        size_t ob = (size_t)(b * 9 + 0) * HW + p;
        float dyv = dy_i[ob], dxv = dx_i[ob], mv = mk_i[ob];
        SETUP(0, dyv, dxv, mv);
    }
    ISSUEG;
    WRITEW(0);
    __syncthreads();

#pragma unroll
    for (int k = 0; k < Kk; ++k) {
        // ---- issue next tap's weight loads FIRST (drain at WRITEW, ~1500cy away)
        if (k < Kk - 1) LOADW(k + 1);

        // ---- issue next tap's offset/mask loads (consumed post-blend) ----
        float dyn = 0.f, dxn = 0.f, mn = 0.f;
        if (k < Kk - 1) {
            size_t ob = (size_t)(b * 9 + k + 1) * HW + p;
            dyn = dy_i[ob]; dxn = dx_i[ob]; mn = mk_i[ob];
        }

        // ---- blend corners -> A fragments (consumes G(k), wg(k)) ----
        s16x8 afr[4];
#pragma unroll
        for (int kk = 0; kk < 4; ++kk) {
#pragma unroll
            for (int j = 0; j < 8; ++j) {
                float s = wg[0] * bf2f(G[0 * 4 + kk][j])
                        + wg[1] * bf2f(G[1 * 4 + kk][j])
                        + wg[2] * bf2f(G[2 * 4 + kk][j])
                        + wg[3] * bf2f(G[3 * 4 + kk][j]);
                afr[kk][j] = f2bf(s);
            }
        }

        // ---- prefetch next tap: setup + issue 16 gathers into G ----
        if (k < Kk - 1) {
            SETUP(k + 1, dyn, dxn, mn);
            ISSUEG;
        }

        // ---- MFMA(k): A in regs, B from w_lds[k&1] ----
        {
            const int orow = lane & 15;
#pragma unroll
            for (int ot = 0; ot < 8; ++ot) {
                int o = ot * 16 + orow;
#pragma unroll
                for (int kk = 0; kk < 4; ++kk) {
                    int byte = (o * 256 + (kk * 32 + kb8) * 2) ^ ((o & 15) << 4);
                    s16x8 bfr = *(const s16x8*)((char*)w_lds[k & 1] + byte);
                    acc[ot] = __builtin_amdgcn_mfma_f32_16x16x32_bf16(afr[kk], bfr, acc[ot], 0, 0, 0);
                }
            }
        }

        // ---- write next tap's weights (Wr long since landed) ----
        if (k < Kk - 1) WRITEW((k + 1) & 1);
        __syncthreads();   // w(k+1) ready; WAR for next write; drains G loads
    }

#undef SETUP
#undef ISSUEG
#undef LOADW
#undef WRITEW

    // ---- epilogue: D layout col=lane&15 (o), row=(lane>>4)*4+reg (px) ----
#pragma unroll
    for (int ot = 0; ot < 8; ++ot) {
        int o = ot * 16 + (lane & 15);
        float bo = bias[o];
        float4 r;
        r.x = acc[ot][0] + bo;
        r.y = acc[ot][1] + bo;
        r.z = acc[ot][2] + bo;
        r.w = acc[ot][3] + bo;
        *(float4*)(out + ((size_t)(b * On + o)) * HW + p0 + pm + (lane >> 4) * 4) = r;
    }
}

// ---------------------------------------------------------------------------
extern "C" void kernel_launch(void* const* d_in, const int* in_sizes, int n_in,
                              void* d_out, int out_size, void* d_ws, size_t ws_size,
                              hipStream_t stream) {
    const float* x      = (const float*)d_in[0];
    const float* w_off  = (const float*)d_in[1];
    const float* b_off  = (const float*)d_in[2];
    const float* w_mask = (const float*)d_in[3];
    const float* b_mask = (const float*)d_in[4];
    const float* wt     = (const float*)d_in[5];
    const float* bias   = (const float*)d_in[6];
    float* out = (float*)d_out;

    short* xT  = (short*)d_ws;                      // B*HW*C bf16 hi
    short* xLo = xT + (size_t)Bn * HW * Cc;         // B*HW*C bf16 lo
    short* wb  = xLo + (size_t)Bn * HW * Cc;        // K*O*C bf16
    short* wofm_h = wb + Kk * On * Cc;
    short* wofm_l = wofm_h + Kk * 32 * Cc;
    float* dy = (float*)(wofm_l + Kk * 32 * Cc);
    float* dx = dy + (size_t)Bn * 9 * HW;
    float* mk = dx + (size_t)Bn * 9 * HW;

    to_nhwc<<<dim3(HW / 64, Bn), 256, 0, stream>>>(x, xT, xLo);
    prep_w<<<(Kk * On * Cc + 255) / 256, 256, 0, stream>>>(wt, wb);
    prep_wofm<<<(Kk * 32 * Cc + 255) / 256, 256, 0, stream>>>(w_off, w_mask, wofm_h, wofm_l);
    offmask_mfma<<<1600, 256, 0, stream>>>(
        xT, xLo, wofm_h, wofm_l, b_off, b_mask, dy, dx, mk);
    dconv_main<<<1600, 256, 0, stream>>>(
        xT, wb, bias, dy, dx, mk, out);
}

// Round 11
// 303.468 us; speedup vs baseline: 1.5785x; 1.0101x over previous
//
#include <hip/hip_runtime.h>
#include <math.h>

constexpr int Bn = 4, Cc = 128, On = 128, Hh = 160, Ww = 160, Kk = 9;
constexpr int HW = Hh * Ww;          // 25600

typedef __attribute__((ext_vector_type(8))) short s16x8;
typedef __attribute__((ext_vector_type(4))) float f32x4;

__device__ inline float bf2f(short s) {
    union { float f; unsigned u; } v;
    v.u = ((unsigned)(unsigned short)s) << 16;
    return v.f;
}
__device__ inline short f2bf(float f) {
    union { float f; unsigned u; } v;
    v.f = f;
    unsigned r = v.u + 0x7fffu + ((v.u >> 16) & 1u);   // RNE
    return (short)(r >> 16);
}

// ---------------------------------------------------------------------------
// Kernel A1: x (NCHW f32) -> xT (NHWC bf16 hi) + xLo (NHWC bf16 lo).
// ---------------------------------------------------------------------------
__global__ __launch_bounds__(256) void to_nhwc(const float* __restrict__ x,
                                               short* __restrict__ xT,
                                               short* __restrict__ xLo) {
    __shared__ float tile[128][65];
    const int t = threadIdx.x;
    const int p0 = blockIdx.x * 64;
    const int b = blockIdx.y;
#pragma unroll
    for (int i = 0; i < 32; ++i) {
        int c = i * 4 + (t >> 6);
        tile[c][t & 63] = x[((size_t)b * Cc + c) * HW + p0 + (t & 63)];
    }
    __syncthreads();
    const int px = t >> 2, cq = t & 3;
    short* dsth = xT  + ((size_t)(b * HW) + p0 + px) * Cc;
    short* dstl = xLo + ((size_t)(b * HW) + p0 + px) * Cc;
#pragma unroll
    for (int j = 0; j < 8; ++j) {
        int c0 = cq * 4 + j * 16;
        short4 vh, vl;
        float f0 = tile[c0 + 0][px], f1 = tile[c0 + 1][px];
        float f2 = tile[c0 + 2][px], f3 = tile[c0 + 3][px];
        vh.x = f2bf(f0); vh.y = f2bf(f1); vh.z = f2bf(f2); vh.w = f2bf(f3);
        vl.x = f2bf(f0 - bf2f(vh.x));
        vl.y = f2bf(f1 - bf2f(vh.y));
        vl.z = f2bf(f2 - bf2f(vh.z));
        vl.w = f2bf(f3 - bf2f(vh.w));
        *(short4*)(dsth + c0) = vh;
        *(short4*)(dstl + c0) = vl;
    }
}

// ---------------------------------------------------------------------------
// Kernel A2: wt (O,C,3,3) f32 -> wb[k][o][c] bf16
// ---------------------------------------------------------------------------
__global__ void prep_w(const float* __restrict__ wt, short* __restrict__ wb) {
    int idx = blockIdx.x * 256 + threadIdx.x;     // K*O*C = 147456
    if (idx >= Kk * On * Cc) return;
    int c = idx & 127;
    int o = (idx >> 7) & 127;
    int k = idx >> 14;
    wb[idx] = f2bf(wt[(o * Cc + c) * 9 + k]);
}

// ---------------------------------------------------------------------------
// Kernel A3: offset/mask weights -> wofm_{hi,lo}[k][ch32][c].
// ---------------------------------------------------------------------------
__global__ void prep_wofm(const float* __restrict__ w_off,
                          const float* __restrict__ w_mask,
                          short* __restrict__ wh, short* __restrict__ wl) {
    int idx = blockIdx.x * 256 + threadIdx.x;     // 9*32*128 = 36864
    if (idx >= Kk * 32 * Cc) return;
    int c = idx & 127;
    int ch = (idx >> 7) & 31;
    int k = idx >> 12;
    float v = 0.f;
    if (ch < 18)      v = w_off[(ch * Cc + c) * 9 + k];
    else if (ch < 27) v = w_mask[((ch - 18) * Cc + c) * 9 + k];
    short hi = f2bf(v);
    wh[idx] = hi;
    wl[idx] = f2bf(v - bf2f(hi));
}

// ---------------------------------------------------------------------------
// Kernel B: offset/mask conv via MFMA, hi/lo split (unchanged from r8).
// ---------------------------------------------------------------------------
__global__ __launch_bounds__(256) void offmask_mfma(
    const short* __restrict__ xT, const short* __restrict__ xLo,
    const short* __restrict__ wh, const short* __restrict__ wl,
    const float* __restrict__ b_off, const float* __restrict__ b_mask,
    float* __restrict__ dy_o, float* __restrict__ dx_o, float* __restrict__ mk_o)
{
    __shared__ short a_hi[6][2304];
    __shared__ short a_lo[6][2304];

    const int g = blockIdx.x;
    const int orig = (g & 7) * 200 + (g >> 3);
    const int b  = orig / 400;
    const int rem = orig % 400;
    const int h0 = (rem / 10) * 4;
    const int w0 = (rem % 10) * 16;

    const int t = threadIdx.x;

    const short* xh_b = xT  + (size_t)b * HW * Cc;
    const short* xl_b = xLo + (size_t)b * HW * Cc;
#pragma unroll
    for (int j = 0; j < 14; ++j) {
        int ci = j * 256 + t;
        if (ci < 3456) {
            int slot = ci / 576;
            int rem2 = ci % 576;
            int isLo = rem2 >= 288;
            int cj   = isLo ? rem2 - 288 : rem2;
            int pxl  = cj >> 4;
            int ck   = cj & 15;
            int r   = h0 - 1 + slot;
            int col = w0 - 1 + pxl;
            int4 v = make_int4(0, 0, 0, 0);
            if ((unsigned)r < (unsigned)Hh && (unsigned)col < (unsigned)Ww) {
                const short* src = (isLo ? xl_b : xh_b) +
                                   ((size_t)(r * Ww + col)) * Cc + ck * 8;
                v = *(const int4*)src;
            }
            int byte = (pxl * 256 + ck * 16) ^ ((pxl & 7) << 4);
            *(int4*)((char*)(isLo ? a_lo[slot] : a_hi[slot]) + byte) = v;
        }
    }
    __syncthreads();

    const int lane = t & 63, wid = t >> 6;
    const int i  = lane & 15;
    const int kb = (lane >> 4) * 8;

    f32x4 acc[2];
    acc[0] = (f32x4){0.f, 0.f, 0.f, 0.f};
    acc[1] = (f32x4){0.f, 0.f, 0.f, 0.f};

    s16x8 bh[2][2][4], bl[2][2][4];

#pragma unroll
    for (int tile = 0; tile < 2; ++tile) {
        const short* bp = wh + ((size_t)(tile * 16 + i)) * Cc + kb;
        const short* lp = wl + ((size_t)(tile * 16 + i)) * Cc + kb;
#pragma unroll
        for (int kk = 0; kk < 4; ++kk) {
            bh[0][tile][kk] = *(const s16x8*)(bp + kk * 32);
            bl[0][tile][kk] = *(const s16x8*)(lp + kk * 32);
        }
    }

#pragma unroll
    for (int k = 0; k < Kk; ++k) {
        const int cur = k & 1, nxt = cur ^ 1;
        if (k < Kk - 1) {
            const int kn = k + 1;
#pragma unroll
            for (int tile = 0; tile < 2; ++tile) {
                const short* bp = wh + ((size_t)(kn * 32 + tile * 16 + i)) * Cc + kb;
                const short* lp = wl + ((size_t)(kn * 32 + tile * 16 + i)) * Cc + kb;
#pragma unroll
                for (int kk = 0; kk < 4; ++kk) {
                    bh[nxt][tile][kk] = *(const s16x8*)(bp + kk * 32);
                    bl[nxt][tile][kk] = *(const s16x8*)(lp + kk * 32);
                }
            }
        }
        const int ky = k / 3, kxi = k % 3;
        const int slot = wid + ky;
        const int pxl = i + kxi;
        s16x8 ah[4], al[4];
#pragma unroll
        for (int kk = 0; kk < 4; ++kk) {
            int byte = (pxl * 256 + (kk * 32 + kb) * 2) ^ ((pxl & 7) << 4);
            ah[kk] = *(const s16x8*)((char*)a_hi[slot] + byte);
            al[kk] = *(const s16x8*)((char*)a_lo[slot] + byte);
        }
#pragma unroll
        for (int tile = 0; tile < 2; ++tile) {
#pragma unroll
            for (int kk = 0; kk < 4; ++kk) {
                acc[tile] = __builtin_amdgcn_mfma_f32_16x16x32_bf16(ah[kk], bh[cur][tile][kk], acc[tile], 0, 0, 0);
                acc[tile] = __builtin_amdgcn_mfma_f32_16x16x32_bf16(al[kk], bh[cur][tile][kk], acc[tile], 0, 0, 0);
                acc[tile] = __builtin_amdgcn_mfma_f32_16x16x32_bf16(ah[kk], bl[cur][tile][kk], acc[tile], 0, 0, 0);
            }
        }
    }

    const int hr = h0 + wid;
#pragma unroll
    for (int tile = 0; tile < 2; ++tile) {
        int ch = tile * 16 + i;
#pragma unroll
        for (int reg = 0; reg < 4; ++reg) {
            int pxo = (lane >> 4) * 4 + reg;
            int p = hr * Ww + w0 + pxo;
            float v = acc[tile][reg];
            if (ch < 18) {
                int k = ch >> 1;
                v += b_off[ch];
                if (ch & 1) dx_o[(size_t)(b * 9 + k) * HW + p] = v;
                else        dy_o[(size_t)(b * 9 + k) * HW + p] = v;
            } else if (ch < 27) {
                int k = ch - 18;
                v += b_mask[k];
                mk_o[(size_t)(b * 9 + k) * HW + p] = 1.f / (1.f + expf(-v));
            }
        }
    }
}

// ---------------------------------------------------------------------------
// Kernel C: main deformable conv — r10 with ONE edit: 2-deep gather pipeline.
// G, wg, omv double-buffered; SETUP(k+1)+ISSUEG(k+1) at TOP of iter k, so the
// per-k barrier's vmcnt(0) drain no longer waits on fresh gathers.
// Numerics identical to r10 (same blend order, f2bf, MFMA sequence).
// ---------------------------------------------------------------------------
__global__ __launch_bounds__(256) void dconv_main(
    const short* __restrict__ xT,    // [b][hw][c] bf16
    const short* __restrict__ wb,    // [k][o][c] bf16
    const float* __restrict__ bias,
    const float* __restrict__ dy_i, const float* __restrict__ dx_i,
    const float* __restrict__ mk_i,
    float* __restrict__ out)
{
    __shared__ short w_lds[2][128 * 128];   // 2 x 32 KB, byte ^= (o&15)<<4

    const int g = blockIdx.x;
    const int orig = (g & 7) * 200 + (g >> 3);
    const int b = orig / 400;
    const int p0 = (orig % 400) * 64;

    const int t = threadIdx.x;
    const int lane = t & 63;
    const int wid = t >> 6;
    const int pm = wid * 16;

    const int myPx = pm + (lane & 15);
    const int p = p0 + myPx;
    const int h = p / Ww, w = p % Ww;
    const int kb8 = (lane >> 4) * 8;

    const short* xbase = xT + (size_t)b * HW * Cc + kb8;

    f32x4 acc[8];
#pragma unroll
    for (int i = 0; i < 8; ++i) acc[i] = (f32x4){0.f, 0.f, 0.f, 0.f};

    float wgbuf[2][4];   // bilinear weights, double-buffered
    int   idxc[4];       // scratch (consumed immediately by ISSUEG)
    s16x8 G[2][16];      // gather regs, double-buffered
    float omv[2][3];     // om scalars, 2 taps ahead
    int4  Wr[8];

#define SETUP(kq, wbuf, dyv, dxv, mv)                                          \
    {                                                                          \
        float py  = (float)(h + ((kq) / 3) - 1) + (dyv);                       \
        float pxf = (float)(w + ((kq) % 3) - 1) + (dxv);                       \
        float y0f = floorf(py), x0f = floorf(pxf);                             \
        float ly = py - y0f, lx = pxf - x0f;                                   \
        int y0 = (int)y0f, x0 = (int)x0f;                                      \
        _Pragma("unroll")                                                      \
        for (int cr = 0; cr < 4; ++cr) {                                       \
            int iy = y0 + (cr >> 1), ix = x0 + (cr & 1);                       \
            bool ok = ((unsigned)iy < (unsigned)Hh) && ((unsigned)ix < (unsigned)Ww); \
            float wy = (cr >> 1) ? ly : (1.f - ly);                            \
            float wx = (cr & 1) ? lx : (1.f - lx);                             \
            int cy = min(max(iy, 0), Hh - 1);                                  \
            int cx = min(max(ix, 0), Ww - 1);                                  \
            idxc[cr] = cy * Ww + cx;                                           \
            wgbuf[wbuf][cr] = ok ? (wy * wx * (mv)) : 0.f;                     \
        }                                                                      \
    }

#define ISSUEG(gbuf)                                                           \
    {                                                                          \
        _Pragma("unroll")                                                      \
        for (int cr = 0; cr < 4; ++cr) {                                       \
            const short* src = xbase + (size_t)idxc[cr] * Cc;                  \
            _Pragma("unroll")                                                  \
            for (int kk = 0; kk < 4; ++kk)                                     \
                G[gbuf][cr * 4 + kk] = *(const s16x8*)(src + kk * 32);         \
        }                                                                      \
    }

#define LOADOM(kq, obuf)                                                       \
    {                                                                          \
        size_t ob = (size_t)(b * 9 + (kq)) * HW + p;                           \
        omv[obuf][0] = dy_i[ob]; omv[obuf][1] = dx_i[ob]; omv[obuf][2] = mk_i[ob]; \
    }

#define LOADW(kq)                                                              \
    {                                                                          \
        const int4* src = (const int4*)(wb + (size_t)(kq) * 128 * 128);        \
        _Pragma("unroll")                                                      \
        for (int i2 = 0; i2 < 8; ++i2) Wr[i2] = src[i2 * 256 + t];             \
    }

#define WRITEW(bufIdx)                                                         \
    {                                                                          \
        _Pragma("unroll")                                                      \
        for (int i2 = 0; i2 < 8; ++i2) {                                       \
            int ci = i2 * 256 + t;                                             \
            int o = ci >> 4;                                                   \
            int byte = (ci << 4) ^ ((o & 15) << 4);                            \
            *(int4*)((char*)w_lds[bufIdx] + byte) = Wr[i2];                    \
        }                                                                      \
    }

    // ---- prologue ----
    LOADW(0);
    LOADOM(0, 0);
    LOADOM(1, 1);
    SETUP(0, 0, omv[0][0], omv[0][1], omv[0][2]);
    ISSUEG(0);
    WRITEW(0);
    __syncthreads();

#pragma unroll
    for (int k = 0; k < Kk; ++k) {
        // ---- top-of-iter issues: land before this iteration's barrier ----
        if (k < Kk - 1) LOADW(k + 1);
        if (k < Kk - 2) LOADOM(k + 2, k & 1);     // omv[k&1] consumed at SETUP(k)
        if (k < Kk - 1) {
            SETUP(k + 1, (k + 1) & 1,
                  omv[(k + 1) & 1][0], omv[(k + 1) & 1][1], omv[(k + 1) & 1][2]);
            ISSUEG((k + 1) & 1);
        }

        // ---- blend(k): consumes G[k&1], wgbuf[k&1] (landed last iteration) ----
        s16x8 afr[4];
#pragma unroll
        for (int kk = 0; kk < 4; ++kk) {
#pragma unroll
            for (int j = 0; j < 8; ++j) {
                float sv = wgbuf[k & 1][0] * bf2f(G[k & 1][0 * 4 + kk][j])
                         + wgbuf[k & 1][1] * bf2f(G[k & 1][1 * 4 + kk][j])
                         + wgbuf[k & 1][2] * bf2f(G[k & 1][2 * 4 + kk][j])
                         + wgbuf[k & 1][3] * bf2f(G[k & 1][3 * 4 + kk][j]);
                afr[kk][j] = f2bf(sv);
            }
        }

        // ---- MFMA(k): A in regs, B from w_lds[k&1] ----
        {
            const int orow = lane & 15;
#pragma unroll
            for (int ot = 0; ot < 8; ++ot) {
                int o = ot * 16 + orow;
#pragma unroll
                for (int kk = 0; kk < 4; ++kk) {
                    int byte = (o * 256 + (kk * 32 + kb8) * 2) ^ ((o & 15) << 4);
                    s16x8 bfr = *(const s16x8*)((char*)w_lds[k & 1] + byte);
                    acc[ot] = __builtin_amdgcn_mfma_f32_16x16x32_bf16(afr[kk], bfr, acc[ot], 0, 0, 0);
                }
            }
        }

        // ---- write next tap's weights (Wr long landed) ----
        if (k < Kk - 1) WRITEW((k + 1) & 1);
        __syncthreads();
    }

#undef SETUP
#undef ISSUEG
#undef LOADOM
#undef LOADW
#undef WRITEW

    // ---- epilogue ----
#pragma unroll
    for (int ot = 0; ot < 8; ++ot) {
        int o = ot * 16 + (lane & 15);
        float bo = bias[o];
        float4 r;
        r.x = acc[ot][0] + bo;
        r.y = acc[ot][1] + bo;
        r.z = acc[ot][2] + bo;
        r.w = acc[ot][3] + bo;
        *(float4*)(out + ((size_t)(b * On + o)) * HW + p0 + pm + (lane >> 4) * 4) = r;
    }
}

// ---------------------------------------------------------------------------
extern "C" void kernel_launch(void* const* d_in, const int* in_sizes, int n_in,
                              void* d_out, int out_size, void* d_ws, size_t ws_size,
                              hipStream_t stream) {
    const float* x      = (const float*)d_in[0];
    const float* w_off  = (const float*)d_in[1];
    const float* b_off  = (const float*)d_in[2];
    const float* w_mask = (const float*)d_in[3];
    const float* b_mask = (const float*)d_in[4];
    const float* wt     = (const float*)d_in[5];
    const float* bias   = (const float*)d_in[6];
    float* out = (float*)d_out;

    short* xT  = (short*)d_ws;                      // B*HW*C bf16 hi
    short* xLo = xT + (size_t)Bn * HW * Cc;         // B*HW*C bf16 lo
    short* wb  = xLo + (size_t)Bn * HW * Cc;        // K*O*C bf16
    short* wofm_h = wb + Kk * On * Cc;
    short* wofm_l = wofm_h + Kk * 32 * Cc;
    float* dy = (float*)(wofm_l + Kk * 32 * Cc);
    float* dx = dy + (size_t)Bn * 9 * HW;
    float* mk = dx + (size_t)Bn * 9 * HW;

    to_nhwc<<<dim3(HW / 64, Bn), 256, 0, stream>>>(x, xT, xLo);
    prep_w<<<(Kk * On * Cc + 255) / 256, 256, 0, stream>>>(wt, wb);
    prep_wofm<<<(Kk * 32 * Cc + 255) / 256, 256, 0, stream>>>(w_off, w_mask, wofm_h, wofm_l);
    offmask_mfma<<<1600, 256, 0, stream>>>(
        xT, xLo, wofm_h, wofm_l, b_off, b_mask, dy, dx, mk);
    dconv_main<<<1600, 256, 0, stream>>>(
        xT, wb, bias, dy, dx, mk, out);
}